// Round 15
// baseline (817.567 us; speedup 1.0000x reference)
//
#include <hip/hip_runtime.h>
#include <hip/hip_fp16.h>
#include <cstdint>

#define HID 128

typedef __attribute__((ext_vector_type(8))) _Float16 f16x8;
typedef __attribute__((ext_vector_type(2))) _Float16 h2v;
typedef __attribute__((ext_vector_type(4))) float f32x4;

__device__ __forceinline__ unsigned short f2h(float x) {
    return __builtin_bit_cast(unsigned short, (_Float16)x);
}
__device__ __forceinline__ float h2f(unsigned short u) {
    return (float)__builtin_bit_cast(_Float16, u);
}
__device__ __forceinline__ h2v mkh2(unsigned short a, unsigned short b) {
    unsigned v = (unsigned)a | ((unsigned)b << 16);
    return __builtin_bit_cast(h2v, v);
}
__device__ __forceinline__ h2v splath(unsigned short a) {
    _Float16 h = __builtin_bit_cast(_Float16, a);
    h2v r; r[0] = h; r[1] = h;
    return r;
}
__device__ __forceinline__ float fdot2v(h2v a, h2v b, float c) {
    return __builtin_amdgcn_fdot2(a, b, c, false);
}
__device__ __forceinline__ int lower_bound_i(const int* a, int n, int v) {
    int lo = 0, hi = n;
    while (lo < hi) { int m = (lo + hi) >> 1; if (a[m] < v) lo = m + 1; else hi = m; }
    return lo;
}

// ---------------------------------------------------------------- mean of edge_attr + degree (fused)
__global__ __launch_bounds__(256) void meandeg_kernel(const int* __restrict__ ei,
                                                      const float* __restrict__ eattr,
                                                      int* __restrict__ deg,
                                                      float* __restrict__ meansum,
                                                      int E, int ET) {
    int e = blockIdx.x * 256 + threadIdx.x;
    float sx = 0.f, sy = 0.f;
    if (e < ET) {
        int dst = (e < E) ? ei[E + e] : (e - E);
        atomicAdd(&deg[dst], 1);
        if (e < E) {
            float2 v = *(const float2*)(eattr + 2 * (size_t)e);
            sx = v.x; sy = v.y;
        }
    }
    for (int d = 1; d < 64; d <<= 1) { sx += __shfl_xor(sx, d); sy += __shfl_xor(sy, d); }
    if ((threadIdx.x & 63) == 0 && (sx != 0.f || sy != 0.f)) {
        atomicAdd(&meansum[0], sx); atomicAdd(&meansum[1], sy);
    }
}

__global__ __launch_bounds__(256) void scanA_kernel(const int* __restrict__ deg,
                                                    int* __restrict__ bsum, int N) {
    __shared__ int ws[4];
    int t = threadIdx.x;
    int base = blockIdx.x * 1024 + t * 4;
    int s = 0;
    #pragma unroll
    for (int j = 0; j < 4; j++) { int idx = base + j; if (idx < N) s += deg[idx]; }
    for (int d = 1; d < 64; d <<= 1) s += __shfl_xor(s, d);
    if ((t & 63) == 0) ws[t >> 6] = s;
    __syncthreads();
    if (t == 0) bsum[blockIdx.x] = ws[0] + ws[1] + ws[2] + ws[3];
}

__global__ __launch_bounds__(64) void scanB_kernel(const int* __restrict__ bsum,
                                                   int* __restrict__ boff,
                                                   int* __restrict__ row_ptr, int NB, int N) {
    int t = threadIdx.x;
    int v = (t < NB) ? bsum[t] : 0;
    int inc = v;
    #pragma unroll
    for (int d = 1; d < 64; d <<= 1) { int u = __shfl_up(inc, d); if (t >= d) inc += u; }
    if (t < NB) boff[t] = inc - v;
    if (t == 63) row_ptr[N] = inc;
}

__global__ __launch_bounds__(256) void scanC_kernel(const int* __restrict__ deg,
                                                    const int* __restrict__ boff,
                                                    int* __restrict__ row_ptr,
                                                    int* __restrict__ cursor, int N) {
    __shared__ int wsum[4];
    int t = threadIdx.x;
    int lane = t & 63, wid = t >> 6;
    int base = blockIdx.x * 1024 + t * 4;
    int v[4]; int s = 0;
    #pragma unroll
    for (int j = 0; j < 4; j++) { int idx = base + j; v[j] = (idx < N) ? deg[idx] : 0; s += v[j]; }
    int inc = s;
    #pragma unroll
    for (int d = 1; d < 64; d <<= 1) { int u = __shfl_up(inc, d); if (lane >= d) inc += u; }
    if (lane == 63) wsum[wid] = inc;
    __syncthreads();
    int woff = 0;
    for (int ww = 0; ww < wid; ww++) woff += wsum[ww];
    int excl = boff[blockIdx.x] + woff + inc - s;
    #pragma unroll
    for (int j = 0; j < 4; j++) {
        int idx = base + j;
        if (idx < N) { row_ptr[idx] = excl; cursor[idx] = excl; }
        excl += v[j];
    }
}

__global__ __launch_bounds__(256) void fill_kernel(const int* __restrict__ ei,
                                                   const float* __restrict__ eattr,
                                                   const float* __restrict__ meansum,
                                                   int* __restrict__ cursor,
                                                   int* __restrict__ csr_src,
                                                   unsigned int* __restrict__ csr_eap,
                                                   int E, int ET) {
    int e = blockIdx.x * 256 + threadIdx.x;
    if (e >= ET) return;
    int src, dst; float2 ea;
    if (e < E) {
        src = ei[e]; dst = ei[E + e];
        ea = *(const float2*)(eattr + 2 * (size_t)e);
    } else {
        src = dst = e - E;
        float inv = 1.0f / (float)E;
        ea.x = meansum[0] * inv; ea.y = meansum[1] * inv;
    }
    unsigned pea = (unsigned)f2h(ea.x) | ((unsigned)f2h(ea.y) << 16);   // fp16 pair
    int pos = atomicAdd(&cursor[dst], 1);
    csr_src[pos] = src;
    csr_eap[pos] = pea;
}

// ---------------------------------------------------------------- weight prep: 3 matrices in one dispatch
__global__ __launch_bounds__(256) void wprep_kernel(const float* __restrict__ s0,
                                                    const float* __restrict__ s1,
                                                    const float* __restrict__ s2,
                                                    unsigned short* __restrict__ d0,
                                                    unsigned short* __restrict__ d1,
                                                    unsigned short* __restrict__ d2, int total) {
    int y = blockIdx.y;
    const float* src = (y == 0) ? s0 : (y == 1) ? s1 : s2;
    unsigned short* dst = (y == 0) ? d0 : (y == 1) ? d1 : d2;
    int idx = blockIdx.x * 256 + threadIdx.x;
    if (idx >= total) return;
    int layer = idx >> 14;
    int rem = idx & 16383;
    int n = rem >> 7, k = rem & 127;
    dst[idx] = f2h(src[(layer << 14) | (k << 7) | n]);
}

// ---------------------------------------------------------------- 3-GEMM sequential: A(fp16) loaded ONCE, W(fp16)
// staged per-matrix in LDS; 64-row blocks; swapped operands -> packed ushort4 stores (fp16).
#define LROW 136
__global__ __launch_bounds__(256) void gemm3_kernel(
    const unsigned short* __restrict__ Hb,
    const unsigned short* __restrict__ W0h, const float* __restrict__ b0, unsigned short* __restrict__ o0,
    const unsigned short* __restrict__ W1h, const float* __restrict__ b1, unsigned short* __restrict__ o1,
    const unsigned short* __restrict__ W2h, const float* __restrict__ b2, unsigned short* __restrict__ o2,
    int N) {
    __shared__ unsigned short lds_h[128 * LROW];
    int tid = threadIdx.x;
    int wid = tid >> 6, lane = tid & 63;
    int row0 = blockIdx.x * 64 + wid * 16;
    int lr = lane & 15;
    int cgrp = lane >> 4;
    int kb = cgrp * 8;
    bool rowsok = (row0 < N);

    f16x8 ha[4];
    {
        int node = row0 + lr;
        int nodec = rowsok ? ((node < N) ? node : (N - 1)) : 0;
        const unsigned short* pa = Hb + (size_t)nodec * HID + kb;
        #pragma unroll
        for (int kf = 0; kf < 4; kf++) ha[kf] = *(const f16x8*)(pa + kf * 32);
    }

    const unsigned short* Whs[3] = {W0h, W1h, W2h};
    const float* Bs[3] = {b0, b1, b2};
    unsigned short* Os[3] = {o0, o1, o2};

    for (int w = 0; w < 3; w++) {
        if (w) __syncthreads();
        const unsigned short* sh = Whs[w];
        #pragma unroll
        for (int j = 0; j < 8; j++) {
            int c = tid + 256 * j;
            int r = c >> 4, col = (c & 15) * 8;
            *(f16x8*)&lds_h[r * LROW + col] = *(const f16x8*)(sh + r * HID + col);
        }
        __syncthreads();
        if (!rowsok) continue;

        const float* bias = Bs[w];
        unsigned short* outp = Os[w];
        #pragma unroll 2
        for (int nf = 0; nf < 8; nf++) {
            int wrow = nf * 16 + lr;
            const unsigned short* ph = &lds_h[wrow * LROW + kb];
            f16x8 wf[4];
            #pragma unroll
            for (int kf = 0; kf < 4; kf++) wf[kf] = *(const f16x8*)(ph + kf * 32);
            f32x4 acc = {0.f, 0.f, 0.f, 0.f};
            #pragma unroll
            for (int kf = 0; kf < 4; kf++)
                acc = __builtin_amdgcn_mfma_f32_16x16x32_f16(wf[kf], ha[kf], acc, 0, 0, 0);
            int chb = nf * 16 + cgrp * 4;
            float4 bias4 = *(const float4*)(bias + chb);
            int node = row0 + lr;
            ushort4 u;
            u.x = f2h(acc[0] + bias4.x); u.y = f2h(acc[1] + bias4.y);
            u.z = f2h(acc[2] + bias4.z); u.w = f2h(acc[3] + bias4.w);
            if (node < N) *(ushort4*)(outp + (size_t)node * HID + chb) = u;
        }
    }
}

// ---------------------------------------------------------------- layer-1 transform (K=16, f32 in -> fp16 out)
__global__ __launch_bounds__(256) void transform16_kernel(
    const float* __restrict__ Hin,
    const float* __restrict__ W0, const float* __restrict__ b0, unsigned short* __restrict__ o0,
    const float* __restrict__ W1, const float* __restrict__ b1, unsigned short* __restrict__ o1,
    int N) {
    constexpr int K = 16;
    __shared__ float Ws[K][HID];
    __shared__ float Hs[32][K + 4];

    const float* W; const float* bias; unsigned short* outp;
    if (blockIdx.z == 0) { W = W0; bias = b0; outp = o0; }
    else                 { W = W1; bias = b1; outp = o1; }

    int row0 = blockIdx.x * 32;
    int tid = threadIdx.x;
    int tx = tid & 15, ty = tid >> 4;

    for (int i = tid; i < 32 * (K / 4); i += 256) {
        int r = i / (K / 4), kq = i % (K / 4);
        int row = row0 + r;
        float4 v = make_float4(0.f, 0.f, 0.f, 0.f);
        if (row < N) v = *(const float4*)(Hin + (size_t)row * K + kq * 4);
        *(float4*)&Hs[r][kq * 4] = v;
    }
    for (int i = tid; i < K * 32; i += 256) {
        int k = i >> 5, cq = i & 31;
        *(float4*)&Ws[k][cq * 4] = *(const float4*)(W + (size_t)k * HID + cq * 4);
    }
    __syncthreads();

    float acc[2][8];
    #pragma unroll
    for (int i = 0; i < 2; i++)
        #pragma unroll
        for (int j = 0; j < 8; j++) acc[i][j] = 0.f;

    int r0 = ty * 2, r1 = ty * 2 + 1;
    #pragma unroll
    for (int k = 0; k < K; k++) {
        float a0 = Hs[r0][k];
        float a1 = Hs[r1][k];
        float4 w0 = *(float4*)&Ws[k][tx * 4];
        float4 w1 = *(float4*)&Ws[k][64 + tx * 4];
        acc[0][0] += a0 * w0.x; acc[0][1] += a0 * w0.y; acc[0][2] += a0 * w0.z; acc[0][3] += a0 * w0.w;
        acc[0][4] += a0 * w1.x; acc[0][5] += a0 * w1.y; acc[0][6] += a0 * w1.z; acc[0][7] += a0 * w1.w;
        acc[1][0] += a1 * w0.x; acc[1][1] += a1 * w0.y; acc[1][2] += a1 * w0.z; acc[1][3] += a1 * w0.w;
        acc[1][4] += a1 * w1.x; acc[1][5] += a1 * w1.y; acc[1][6] += a1 * w1.z; acc[1][7] += a1 * w1.w;
    }

    float4 bb0 = *(const float4*)(bias + tx * 4);
    float4 bb1 = *(const float4*)(bias + 64 + tx * 4);
    #pragma unroll
    for (int i = 0; i < 2; i++) {
        int row = row0 + ty * 2 + i;
        if (row < N) {
            ushort4 h0, h1;
            h0.x = f2h(acc[i][0] + bb0.x); h0.y = f2h(acc[i][1] + bb0.y);
            h0.z = f2h(acc[i][2] + bb0.z); h0.w = f2h(acc[i][3] + bb0.w);
            h1.x = f2h(acc[i][4] + bb1.x); h1.y = f2h(acc[i][5] + bb1.y);
            h1.z = f2h(acc[i][6] + bb1.z); h1.w = f2h(acc[i][7] + bb1.w);
            *(ushort4*)(outp + (size_t)row * HID + tx * 4) = h0;
            *(ushort4*)(outp + (size_t)row * HID + 64 + tx * 4) = h1;
        }
    }
}

// ---------------------------------------------------------------- layer-1 combine: Hb = fp16(elu(att(fp16) + x@W + b))
__global__ __launch_bounds__(256) void combine16_kernel(
    const float* __restrict__ Hin,
    const float* __restrict__ W, const float* __restrict__ bias,
    const unsigned short* __restrict__ Att, unsigned short* __restrict__ Hb,
    int N) {
    constexpr int K = 16;
    __shared__ float Ws[K][HID];
    __shared__ float Hs[32][K + 4];

    int row0 = blockIdx.x * 32;
    int tid = threadIdx.x;
    int tx = tid & 15, ty = tid >> 4;

    for (int i = tid; i < 32 * (K / 4); i += 256) {
        int r = i / (K / 4), kq = i % (K / 4);
        int row = row0 + r;
        float4 v = make_float4(0.f, 0.f, 0.f, 0.f);
        if (row < N) v = *(const float4*)(Hin + (size_t)row * K + kq * 4);
        *(float4*)&Hs[r][kq * 4] = v;
    }
    for (int i = tid; i < K * 32; i += 256) {
        int k = i >> 5, cq = i & 31;
        *(float4*)&Ws[k][cq * 4] = *(const float4*)(W + (size_t)k * HID + cq * 4);
    }
    __syncthreads();

    float acc[2][8];
    #pragma unroll
    for (int i = 0; i < 2; i++)
        #pragma unroll
        for (int j = 0; j < 8; j++) acc[i][j] = 0.f;

    int r0 = ty * 2, r1 = ty * 2 + 1;
    #pragma unroll
    for (int k = 0; k < K; k++) {
        float a0 = Hs[r0][k];
        float a1 = Hs[r1][k];
        float4 w0 = *(float4*)&Ws[k][tx * 4];
        float4 w1 = *(float4*)&Ws[k][64 + tx * 4];
        acc[0][0] += a0 * w0.x; acc[0][1] += a0 * w0.y; acc[0][2] += a0 * w0.z; acc[0][3] += a0 * w0.w;
        acc[0][4] += a0 * w1.x; acc[0][5] += a0 * w1.y; acc[0][6] += a0 * w1.z; acc[0][7] += a0 * w1.w;
        acc[1][0] += a1 * w0.x; acc[1][1] += a1 * w0.y; acc[1][2] += a1 * w0.z; acc[1][3] += a1 * w0.w;
        acc[1][4] += a1 * w1.x; acc[1][5] += a1 * w1.y; acc[1][6] += a1 * w1.z; acc[1][7] += a1 * w1.w;
    }

    float4 bb0 = *(const float4*)(bias + tx * 4);
    float4 bb1 = *(const float4*)(bias + 64 + tx * 4);
    #pragma unroll
    for (int i = 0; i < 2; i++) {
        int row = row0 + ty * 2 + i;
        if (row < N) {
            const unsigned short* p0 = Att + (size_t)row * HID + tx * 4;
            ushort4 g0 = *(const ushort4*)p0;
            ushort4 g1 = *(const ushort4*)(p0 + 64);
            float v[8];
            v[0] = h2f(g0.x) + acc[i][0] + bb0.x; v[1] = h2f(g0.y) + acc[i][1] + bb0.y;
            v[2] = h2f(g0.z) + acc[i][2] + bb0.z; v[3] = h2f(g0.w) + acc[i][3] + bb0.w;
            v[4] = h2f(g1.x) + acc[i][4] + bb1.x; v[5] = h2f(g1.y) + acc[i][5] + bb1.y;
            v[6] = h2f(g1.z) + acc[i][6] + bb1.z; v[7] = h2f(g1.w) + acc[i][7] + bb1.w;
            #pragma unroll
            for (int j = 0; j < 8; j++) v[j] = (v[j] > 0.f) ? v[j] : (__expf(v[j]) - 1.f);
            ushort4 h0, h1;
            h0.x = f2h(v[0]); h0.y = f2h(v[1]); h0.z = f2h(v[2]); h0.w = f2h(v[3]);
            h1.x = f2h(v[4]); h1.y = f2h(v[5]); h1.z = f2h(v[6]); h1.w = f2h(v[7]);
            *(ushort4*)(Hb + (size_t)row * HID + tx * 4) = h0;
            *(ushort4*)(Hb + (size_t)row * HID + 64 + tx * 4) = h1;
        }
    }
}

// ---------------------------------------------------------------- edge: packed _Float16 vector math.
// ONE node/wave; halves split edge list; no running max (logits O(1), clamp 60); plain-sum accumulators.
// FUSE=0 (layer 1): output att+gbias as fp16 -> hb.  FUSE=1: +lin, elu, fp16 -> hb (+f32 hf if non-null).
template <int FUSE>
__global__ __launch_bounds__(256) void edgeh_kernel(
    const unsigned short* __restrict__ XL, const unsigned short* __restrict__ XR,
    const int* __restrict__ row_ptr, const int* __restrict__ csr_src,
    const unsigned int* __restrict__ csr_eap,
    const float* __restrict__ att,
    const float* __restrict__ We,
    const float* __restrict__ gbias,
    const unsigned short* __restrict__ lin,
    float* __restrict__ hf, unsigned short* __restrict__ hb,
    int N) {
    int n = (blockIdx.x * 256 + threadIdx.x) >> 6;
    int lane = threadIdx.x & 63;
    int half = lane >> 5;
    int l = lane & 31;
    bool active = (n < N);
    int nn = active ? n : 0;

    int c0 = l * 4;
    float4 avf = *(const float4*)(att + c0);
    float4 w0f = *(const float4*)(We + c0);
    float4 w1f = *(const float4*)(We + HID + c0);
    h2v avA; avA[0] = (_Float16)avf.x; avA[1] = (_Float16)avf.y;
    h2v avB; avB[0] = (_Float16)avf.z; avB[1] = (_Float16)avf.w;
    h2v weA0; weA0[0] = (_Float16)w0f.x; weA0[1] = (_Float16)w0f.y;
    h2v weB0; weB0[0] = (_Float16)w0f.z; weB0[1] = (_Float16)w0f.w;
    h2v weA1; weA1[0] = (_Float16)w1f.x; weA1[1] = (_Float16)w1f.y;
    h2v weB1; weB1[0] = (_Float16)w1f.z; weB1[1] = (_Float16)w1f.w;
    h2v k02; k02[0] = (_Float16)0.2f; k02[1] = (_Float16)0.2f;

    ushort4 xru = *(const ushort4*)(XR + (size_t)nn * HID + c0);
    h2v xrA = mkh2(xru.x, xru.y), xrB = mkh2(xru.z, xru.w);

    int eb = 0, eend = 0;
    if (active) { eb = row_ptr[n]; eend = row_ptr[n + 1]; }
    int mid = (eb + eend + 1) >> 1;
    int sb = half ? mid : eb;
    int se = half ? eend : mid;

    float l_run = 0.f;
    float4 fa = make_float4(0.f, 0.f, 0.f, 0.f);

    for (int base = sb; base < se; base += 32) {
        int cnt = min(32, se - base);
        int myi = base + l;
        int msrc = 0; unsigned mea = 0;
        if (myi < se) { msrc = csr_src[myi]; mea = csr_eap[myi]; }

        int s0 = __shfl(msrc, 0, 32);
        int s1 = __shfl(msrc, 1, 32);
        unsigned e0 = __shfl(mea, 0, 32);
        unsigned e1 = __shfl(mea, 1, 32);
        ushort4 u0 = *(const ushort4*)(XL + (size_t)s0 * HID + c0);
        ushort4 u1 = *(const ushort4*)(XL + (size_t)s1 * HID + c0);

        for (int j = 0; ; j += 2) {
            bool more = (j + 2 < cnt);
            int ns0 = 0, ns1 = 0; unsigned ne0 = 0, ne1 = 0;
            ushort4 nu0, nu1;
            if (more) {
                ns0 = __shfl(msrc, j + 2, 32);
                ns1 = __shfl(msrc, j + 3, 32);
                ne0 = __shfl(mea, j + 2, 32);
                ne1 = __shfl(mea, j + 3, 32);
                nu0 = *(const ushort4*)(XL + (size_t)ns0 * HID + c0);
                nu1 = *(const ushort4*)(XL + (size_t)ns1 * HID + c0);
            }
            h2v ex0 = splath((unsigned short)(e0 & 0xffff));
            h2v ey0 = splath((unsigned short)(e0 >> 16));
            h2v ex1 = splath((unsigned short)(e1 & 0xffff));
            h2v ey1 = splath((unsigned short)(e1 >> 16));
            h2v xl0A = mkh2(u0.x, u0.y), xl0B = mkh2(u0.z, u0.w);
            h2v xl1A = mkh2(u1.x, u1.y), xl1B = mkh2(u1.z, u1.w);

            h2v mA = xl0A + xrA + ex0 * weA0 + ey0 * weA1;
            mA = __builtin_elementwise_max(mA, k02 * mA);
            h2v mB = xl0B + xrB + ex0 * weB0 + ey0 * weB1;
            mB = __builtin_elementwise_max(mB, k02 * mB);
            float part0 = fdot2v(mB, avB, fdot2v(mA, avA, 0.f));

            h2v nA = xl1A + xrA + ex1 * weA0 + ey1 * weA1;
            nA = __builtin_elementwise_max(nA, k02 * nA);
            h2v nB = xl1B + xrB + ex1 * weB0 + ey1 * weB1;
            nB = __builtin_elementwise_max(nB, k02 * nB);
            float part1 = fdot2v(nB, avB, fdot2v(nA, avA, 0.f));

            float t;
            t = __shfl_xor(part0, 1); part0 += t;
            t = __shfl_xor(part0, 2); part0 += t;
            t = __shfl_xor(part1, 1); part1 += t;
            t = __shfl_xor(part1, 2); part1 += t;

            bool two = (j + 1 < cnt);
            float p0 = __expf(fminf(part0, 60.f));
            float p1 = two ? __expf(fminf(part1, 60.f)) : 0.f;
            l_run += p0 + p1;
            fa.x += p0 * h2f(u0.x) + p1 * h2f(u1.x);
            fa.y += p0 * h2f(u0.y) + p1 * h2f(u1.y);
            fa.z += p0 * h2f(u0.z) + p1 * h2f(u1.z);
            fa.w += p0 * h2f(u0.w) + p1 * h2f(u1.w);
            if (!more) break;
            s0 = ns0; s1 = ns1; e0 = ne0; e1 = ne1; u0 = nu0; u1 = nu1;
        }
    }

    l_run += __shfl_xor(l_run, 32);
    fa.x += __shfl_xor(fa.x, 32);
    fa.y += __shfl_xor(fa.y, 32);
    fa.z += __shfl_xor(fa.z, 32);
    fa.w += __shfl_xor(fa.w, 32);

    if (!active || half) return;
    float inv = 1.f / fmaxf(l_run, 1e-16f);
    float4 bias4 = *(const float4*)(gbias + c0);
    float4 v;
    v.x = fa.x * inv + bias4.x;
    v.y = fa.y * inv + bias4.y;
    v.z = fa.z * inv + bias4.z;
    v.w = fa.w * inv + bias4.w;
    if constexpr (FUSE) {
        ushort4 lu = *(const ushort4*)(lin + (size_t)n * HID + c0);
        v.x += h2f(lu.x); v.y += h2f(lu.y); v.z += h2f(lu.z); v.w += h2f(lu.w);
        v.x = (v.x > 0.f) ? v.x : (__expf(v.x) - 1.f);
        v.y = (v.y > 0.f) ? v.y : (__expf(v.y) - 1.f);
        v.z = (v.z > 0.f) ? v.z : (__expf(v.z) - 1.f);
        v.w = (v.w > 0.f) ? v.w : (__expf(v.w) - 1.f);
        if (hf) *(float4*)(hf + (size_t)n * HID + c0) = v;
    }
    ushort4 hh;
    hh.x = f2h(v.x); hh.y = f2h(v.y); hh.z = f2h(v.z); hh.w = f2h(v.w);
    *(ushort4*)(hb + (size_t)n * HID + c0) = hh;
}

// ---------------------------------------------------------------- mean pool per graph
__global__ __launch_bounds__(128) void pool_kernel(const float* __restrict__ h,
                                                   const int* __restrict__ batch,
                                                   float* __restrict__ g, int N) {
    int gid = blockIdx.x;
    int lo = lower_bound_i(batch, N, gid);
    int hi = lower_bound_i(batch, N, gid + 1);
    int c = threadIdx.x;
    float s = 0.f;
    for (int i = lo; i < hi; i++) s += h[(size_t)i * HID + c];
    g[gid * HID + c] = s / fmaxf((float)(hi - lo), 1.0f);
}

// ---------------------------------------------------------------- readout GEMM
__global__ __launch_bounds__(256) void readout_kernel(const float* __restrict__ g,
                                                      const float* __restrict__ W,
                                                      const float* __restrict__ b,
                                                      float* __restrict__ out, int S) {
    __shared__ float gs[HID];
    int gid = blockIdx.y;
    if (threadIdx.x < HID) gs[threadIdx.x] = g[gid * HID + threadIdx.x];
    __syncthreads();
    int c = blockIdx.x * 256 + threadIdx.x;
    if (c < S) {
        float acc = b[c];
        #pragma unroll 8
        for (int k = 0; k < HID; k++) acc += gs[k] * W[(size_t)k * S + c];
        out[(size_t)gid * S + c] = acc;
    }
}

// ---------------------------------------------------------------- launcher
extern "C" void kernel_launch(void* const* d_in, const int* in_sizes, int n_in,
                              void* d_out, int out_size, void* d_ws, size_t ws_size,
                              hipStream_t stream) {
    const float* x      = (const float*)d_in[0];
    const int*   ei     = (const int*)d_in[1];
    const float* eattr  = (const float*)d_in[2];
    const int*   batch  = (const int*)d_in[3];
    const float* at1_Wl = (const float*)d_in[4];
    const float* at1_bl = (const float*)d_in[5];
    const float* at1_Wr = (const float*)d_in[6];
    const float* at1_br = (const float*)d_in[7];
    const float* at1_We = (const float*)d_in[8];
    const float* at1_att= (const float*)d_in[9];
    const float* at1_b  = (const float*)d_in[10];
    const float* l1_W   = (const float*)d_in[11];
    const float* l1_b   = (const float*)d_in[12];
    const float* atk_Wl = (const float*)d_in[13];
    const float* atk_bl = (const float*)d_in[14];
    const float* atk_Wr = (const float*)d_in[15];
    const float* atk_br = (const float*)d_in[16];
    const float* atk_We = (const float*)d_in[17];
    const float* atk_att= (const float*)d_in[18];
    const float* atk_b  = (const float*)d_in[19];
    const float* lk_W   = (const float*)d_in[20];
    const float* lk_b   = (const float*)d_in[21];
    const float* lin_W  = (const float*)d_in[22];
    const float* lin_b  = (const float*)d_in[23];
    float* out = (float*)d_out;

    const int N  = in_sizes[0] / 16;
    const int E  = in_sizes[1] / 2;
    const int ET = E + N;
    const int S  = 1000;
    const int G  = out_size / S;

    char* w = (char*)d_ws;
    auto alloc = [&](size_t bytes) -> char* {
        char* p = w; w += (bytes + 255) & ~(size_t)255; return p;
    };
    unsigned short* XLb = (unsigned short*)alloc((size_t)N * HID * 2);
    unsigned short* XRb = (unsigned short*)alloc((size_t)N * HID * 2);
    unsigned short* Linb = (unsigned short*)alloc((size_t)N * HID * 2);   // also layer-1 Att buffer
    float*  Hf      = (float*)alloc((size_t)N * HID * 4);
    unsigned short* Hb = (unsigned short*)alloc((size_t)N * HID * 2);
    int*    deg     = (int*)alloc((size_t)N * 4);
    int*    row_ptr = (int*)alloc((size_t)(N + 1) * 4);
    int*    cursor  = (int*)alloc((size_t)N * 4);
    int*    csr_src = (int*)alloc((size_t)ET * 4);
    unsigned int* csr_eap = (unsigned int*)alloc((size_t)ET * 4);
    float*  meansum = (float*)alloc(8);
    int*    bsum    = (int*)alloc(256);
    int*    boff    = (int*)alloc(256);
    unsigned short* WlTh = (unsigned short*)alloc((size_t)9 * 16384 * 2);
    unsigned short* WrTh = (unsigned short*)alloc((size_t)9 * 16384 * 2);
    unsigned short* WkTh = (unsigned short*)alloc((size_t)9 * 16384 * 2);
    float*  gpool   = (float*)alloc((size_t)G * HID * 4);
    (void)ws_size; (void)n_in;

    hipError_t err;
    err = hipMemsetAsync(deg, 0, (size_t)N * 4, stream); (void)err;
    err = hipMemsetAsync(meansum, 0, 8, stream); (void)err;

    const int wtot = 9 * 16384;
    wprep_kernel<<<dim3((wtot + 255) / 256, 3), 256, 0, stream>>>(atk_Wl, atk_Wr, lk_W,
                                                                  WlTh, WrTh, WkTh, wtot);

    meandeg_kernel<<<(ET + 255) / 256, 256, 0, stream>>>(ei, eattr, deg, meansum, E, ET);
    const int NB = (N + 1023) / 1024;
    scanA_kernel<<<NB, 256, 0, stream>>>(deg, bsum, N);
    scanB_kernel<<<1, 64, 0, stream>>>(bsum, boff, row_ptr, NB, N);
    scanC_kernel<<<NB, 256, 0, stream>>>(deg, boff, row_ptr, cursor, N);
    fill_kernel<<<(ET + 255) / 256, 256, 0, stream>>>(ei, eattr, meansum, cursor, csr_src, csr_eap, E, ET);

    const int gx16 = (N + 31) / 32;
    const int ge   = (N + 3) / 4;
    const int gx3  = (N + 63) / 64;

    transform16_kernel<<<dim3(gx16, 1, 2), 256, 0, stream>>>(x, at1_Wl, at1_bl, XLb, at1_Wr, at1_br, XRb, N);
    edgeh_kernel<0><<<ge, 256, 0, stream>>>(XLb, XRb, row_ptr, csr_src, csr_eap, at1_att, at1_We, at1_b,
                                            nullptr, nullptr, Linb, N);
    combine16_kernel<<<gx16, 256, 0, stream>>>(x, l1_W, l1_b, Linb, Hb, N);

    for (int i = 0; i < 9; i++) {
        const unsigned short* wlh = WlTh + (size_t)i * 16384;
        const unsigned short* wrh = WrTh + (size_t)i * 16384;
        const unsigned short* wkh = WkTh + (size_t)i * 16384;
        const float* bl = atk_bl + (size_t)i * HID;
        const float* br = atk_br + (size_t)i * HID;
        const float* bk = lk_b   + (size_t)i * HID;
        const float* Wep = atk_We + (size_t)i * 2 * HID;
        const float* at = atk_att + (size_t)i * HID;
        const float* ab = atk_b  + (size_t)i * HID;

        gemm3_kernel<<<gx3, 256, 0, stream>>>(Hb,
                                              wlh, bl, XLb,
                                              wrh, br, XRb,
                                              wkh, bk, Linb, N);
        edgeh_kernel<1><<<ge, 256, 0, stream>>>(XLb, XRb, row_ptr, csr_src, csr_eap, at, Wep, ab,
                                                Linb, (i == 8) ? Hf : nullptr, Hb, N);
    }

    pool_kernel<<<G, 128, 0, stream>>>(Hf, batch, gpool, N);
    readout_kernel<<<dim3((S + 255) / 256, G), 256, 0, stream>>>(gpool, lin_W, lin_b, out, S);
}

// Round 16
// 696.595 us; speedup vs baseline: 1.1737x; 1.1737x over previous
//
#include <hip/hip_runtime.h>
#include <hip/hip_fp16.h>
#include <cstdint>

#define HID 128

typedef __attribute__((ext_vector_type(8))) _Float16 f16x8;
typedef __attribute__((ext_vector_type(2))) _Float16 h2v;
typedef __attribute__((ext_vector_type(4))) float f32x4;

__device__ __forceinline__ unsigned short f2h(float x) {
    return __builtin_bit_cast(unsigned short, (_Float16)x);
}
__device__ __forceinline__ float h2f(unsigned short u) {
    return (float)__builtin_bit_cast(_Float16, u);
}
__device__ __forceinline__ h2v mkh2(unsigned short a, unsigned short b) {
    unsigned v = (unsigned)a | ((unsigned)b << 16);
    return __builtin_bit_cast(h2v, v);
}
__device__ __forceinline__ h2v splath(unsigned short a) {
    _Float16 h = __builtin_bit_cast(_Float16, a);
    h2v r; r[0] = h; r[1] = h;
    return r;
}
__device__ __forceinline__ float fdot2v(h2v a, h2v b, float c) {
    return __builtin_amdgcn_fdot2(a, b, c, false);
}
__device__ __forceinline__ int lower_bound_i(const int* a, int n, int v) {
    int lo = 0, hi = n;
    while (lo < hi) { int m = (lo + hi) >> 1; if (a[m] < v) lo = m + 1; else hi = m; }
    return lo;
}

// ---------------------------------------------------------------- mean of edge_attr (256 grid-stride blocks:
// only 1024 wave-atomics to the two meansum addresses -- single-address float atomics serialize, so keep count low)
__global__ __launch_bounds__(256) void mean_kernel(const float* __restrict__ eattr,
                                                   float* __restrict__ meansum, int E) {
    float sx = 0.f, sy = 0.f;
    for (int i = blockIdx.x * 256 + threadIdx.x; i < E; i += gridDim.x * 256) {
        float2 v = *(const float2*)(eattr + 2 * (size_t)i);
        sx += v.x; sy += v.y;
    }
    for (int d = 1; d < 64; d <<= 1) { sx += __shfl_xor(sx, d); sy += __shfl_xor(sy, d); }
    if ((threadIdx.x & 63) == 0) { atomicAdd(&meansum[0], sx); atomicAdd(&meansum[1], sy); }
}

// ---------------------------------------------------------------- CSR build
__global__ __launch_bounds__(256) void deg_kernel(const int* __restrict__ ei,
                                                  int* __restrict__ deg, int E, int ET) {
    int e = blockIdx.x * 256 + threadIdx.x;
    if (e >= ET) return;
    int dst = (e < E) ? ei[E + e] : (e - E);
    atomicAdd(&deg[dst], 1);
}

__global__ __launch_bounds__(256) void scanA_kernel(const int* __restrict__ deg,
                                                    int* __restrict__ bsum, int N) {
    __shared__ int ws[4];
    int t = threadIdx.x;
    int base = blockIdx.x * 1024 + t * 4;
    int s = 0;
    #pragma unroll
    for (int j = 0; j < 4; j++) { int idx = base + j; if (idx < N) s += deg[idx]; }
    for (int d = 1; d < 64; d <<= 1) s += __shfl_xor(s, d);
    if ((t & 63) == 0) ws[t >> 6] = s;
    __syncthreads();
    if (t == 0) bsum[blockIdx.x] = ws[0] + ws[1] + ws[2] + ws[3];
}

__global__ __launch_bounds__(64) void scanB_kernel(const int* __restrict__ bsum,
                                                   int* __restrict__ boff,
                                                   int* __restrict__ row_ptr, int NB, int N) {
    int t = threadIdx.x;
    int v = (t < NB) ? bsum[t] : 0;
    int inc = v;
    #pragma unroll
    for (int d = 1; d < 64; d <<= 1) { int u = __shfl_up(inc, d); if (t >= d) inc += u; }
    if (t < NB) boff[t] = inc - v;
    if (t == 63) row_ptr[N] = inc;
}

__global__ __launch_bounds__(256) void scanC_kernel(const int* __restrict__ deg,
                                                    const int* __restrict__ boff,
                                                    int* __restrict__ row_ptr,
                                                    int* __restrict__ cursor, int N) {
    __shared__ int wsum[4];
    int t = threadIdx.x;
    int lane = t & 63, wid = t >> 6;
    int base = blockIdx.x * 1024 + t * 4;
    int v[4]; int s = 0;
    #pragma unroll
    for (int j = 0; j < 4; j++) { int idx = base + j; v[j] = (idx < N) ? deg[idx] : 0; s += v[j]; }
    int inc = s;
    #pragma unroll
    for (int d = 1; d < 64; d <<= 1) { int u = __shfl_up(inc, d); if (lane >= d) inc += u; }
    if (lane == 63) wsum[wid] = inc;
    __syncthreads();
    int woff = 0;
    for (int ww = 0; ww < wid; ww++) woff += wsum[ww];
    int excl = boff[blockIdx.x] + woff + inc - s;
    #pragma unroll
    for (int j = 0; j < 4; j++) {
        int idx = base + j;
        if (idx < N) { row_ptr[idx] = excl; cursor[idx] = excl; }
        excl += v[j];
    }
}

__global__ __launch_bounds__(256) void fill_kernel(const int* __restrict__ ei,
                                                   const float* __restrict__ eattr,
                                                   const float* __restrict__ meansum,
                                                   int* __restrict__ cursor,
                                                   int* __restrict__ csr_src,
                                                   unsigned int* __restrict__ csr_eap,
                                                   int E, int ET) {
    int e = blockIdx.x * 256 + threadIdx.x;
    if (e >= ET) return;
    int src, dst; float2 ea;
    if (e < E) {
        src = ei[e]; dst = ei[E + e];
        ea = *(const float2*)(eattr + 2 * (size_t)e);
    } else {
        src = dst = e - E;
        float inv = 1.0f / (float)E;
        ea.x = meansum[0] * inv; ea.y = meansum[1] * inv;
    }
    unsigned pea = (unsigned)f2h(ea.x) | ((unsigned)f2h(ea.y) << 16);   // fp16 pair
    int pos = atomicAdd(&cursor[dst], 1);
    csr_src[pos] = src;
    csr_eap[pos] = pea;
}

// ---------------------------------------------------------------- weight prep: 3 matrices in one dispatch
__global__ __launch_bounds__(256) void wprep_kernel(const float* __restrict__ s0,
                                                    const float* __restrict__ s1,
                                                    const float* __restrict__ s2,
                                                    unsigned short* __restrict__ d0,
                                                    unsigned short* __restrict__ d1,
                                                    unsigned short* __restrict__ d2, int total) {
    int y = blockIdx.y;
    const float* src = (y == 0) ? s0 : (y == 1) ? s1 : s2;
    unsigned short* dst = (y == 0) ? d0 : (y == 1) ? d1 : d2;
    int idx = blockIdx.x * 256 + threadIdx.x;
    if (idx >= total) return;
    int layer = idx >> 14;
    int rem = idx & 16383;
    int n = rem >> 7, k = rem & 127;
    dst[idx] = f2h(src[(layer << 14) | (k << 7) | n]);
}

// ---------------------------------------------------------------- 3-GEMM sequential: A(fp16) loaded ONCE, W(fp16)
// staged per-matrix in LDS; 64-row blocks; swapped operands -> packed ushort4 stores (fp16).
#define LROW 136
__global__ __launch_bounds__(256) void gemm3_kernel(
    const unsigned short* __restrict__ Hb,
    const unsigned short* __restrict__ W0h, const float* __restrict__ b0, unsigned short* __restrict__ o0,
    const unsigned short* __restrict__ W1h, const float* __restrict__ b1, unsigned short* __restrict__ o1,
    const unsigned short* __restrict__ W2h, const float* __restrict__ b2, unsigned short* __restrict__ o2,
    int N) {
    __shared__ unsigned short lds_h[128 * LROW];
    int tid = threadIdx.x;
    int wid = tid >> 6, lane = tid & 63;
    int row0 = blockIdx.x * 64 + wid * 16;
    int lr = lane & 15;
    int cgrp = lane >> 4;
    int kb = cgrp * 8;
    bool rowsok = (row0 < N);

    f16x8 ha[4];
    {
        int node = row0 + lr;
        int nodec = rowsok ? ((node < N) ? node : (N - 1)) : 0;
        const unsigned short* pa = Hb + (size_t)nodec * HID + kb;
        #pragma unroll
        for (int kf = 0; kf < 4; kf++) ha[kf] = *(const f16x8*)(pa + kf * 32);
    }

    const unsigned short* Whs[3] = {W0h, W1h, W2h};
    const float* Bs[3] = {b0, b1, b2};
    unsigned short* Os[3] = {o0, o1, o2};

    for (int w = 0; w < 3; w++) {
        if (w) __syncthreads();
        const unsigned short* sh = Whs[w];
        #pragma unroll
        for (int j = 0; j < 8; j++) {
            int c = tid + 256 * j;
            int r = c >> 4, col = (c & 15) * 8;
            *(f16x8*)&lds_h[r * LROW + col] = *(const f16x8*)(sh + r * HID + col);
        }
        __syncthreads();
        if (!rowsok) continue;

        const float* bias = Bs[w];
        unsigned short* outp = Os[w];
        #pragma unroll 2
        for (int nf = 0; nf < 8; nf++) {
            int wrow = nf * 16 + lr;
            const unsigned short* ph = &lds_h[wrow * LROW + kb];
            f16x8 wf[4];
            #pragma unroll
            for (int kf = 0; kf < 4; kf++) wf[kf] = *(const f16x8*)(ph + kf * 32);
            f32x4 acc = {0.f, 0.f, 0.f, 0.f};
            #pragma unroll
            for (int kf = 0; kf < 4; kf++)
                acc = __builtin_amdgcn_mfma_f32_16x16x32_f16(wf[kf], ha[kf], acc, 0, 0, 0);
            int chb = nf * 16 + cgrp * 4;
            float4 bias4 = *(const float4*)(bias + chb);
            int node = row0 + lr;
            ushort4 u;
            u.x = f2h(acc[0] + bias4.x); u.y = f2h(acc[1] + bias4.y);
            u.z = f2h(acc[2] + bias4.z); u.w = f2h(acc[3] + bias4.w);
            if (node < N) *(ushort4*)(outp + (size_t)node * HID + chb) = u;
        }
    }
}

// ---------------------------------------------------------------- layer-1 transform (K=16, f32 in -> fp16 out)
__global__ __launch_bounds__(256) void transform16_kernel(
    const float* __restrict__ Hin,
    const float* __restrict__ W0, const float* __restrict__ b0, unsigned short* __restrict__ o0,
    const float* __restrict__ W1, const float* __restrict__ b1, unsigned short* __restrict__ o1,
    int N) {
    constexpr int K = 16;
    __shared__ float Ws[K][HID];
    __shared__ float Hs[32][K + 4];

    const float* W; const float* bias; unsigned short* outp;
    if (blockIdx.z == 0) { W = W0; bias = b0; outp = o0; }
    else                 { W = W1; bias = b1; outp = o1; }

    int row0 = blockIdx.x * 32;
    int tid = threadIdx.x;
    int tx = tid & 15, ty = tid >> 4;

    for (int i = tid; i < 32 * (K / 4); i += 256) {
        int r = i / (K / 4), kq = i % (K / 4);
        int row = row0 + r;
        float4 v = make_float4(0.f, 0.f, 0.f, 0.f);
        if (row < N) v = *(const float4*)(Hin + (size_t)row * K + kq * 4);
        *(float4*)&Hs[r][kq * 4] = v;
    }
    for (int i = tid; i < K * 32; i += 256) {
        int k = i >> 5, cq = i & 31;
        *(float4*)&Ws[k][cq * 4] = *(const float4*)(W + (size_t)k * HID + cq * 4);
    }
    __syncthreads();

    float acc[2][8];
    #pragma unroll
    for (int i = 0; i < 2; i++)
        #pragma unroll
        for (int j = 0; j < 8; j++) acc[i][j] = 0.f;

    int r0 = ty * 2, r1 = ty * 2 + 1;
    #pragma unroll
    for (int k = 0; k < K; k++) {
        float a0 = Hs[r0][k];
        float a1 = Hs[r1][k];
        float4 w0 = *(float4*)&Ws[k][tx * 4];
        float4 w1 = *(float4*)&Ws[k][64 + tx * 4];
        acc[0][0] += a0 * w0.x; acc[0][1] += a0 * w0.y; acc[0][2] += a0 * w0.z; acc[0][3] += a0 * w0.w;
        acc[0][4] += a0 * w1.x; acc[0][5] += a0 * w1.y; acc[0][6] += a0 * w1.z; acc[0][7] += a0 * w1.w;
        acc[1][0] += a1 * w0.x; acc[1][1] += a1 * w0.y; acc[1][2] += a1 * w0.z; acc[1][3] += a1 * w0.w;
        acc[1][4] += a1 * w1.x; acc[1][5] += a1 * w1.y; acc[1][6] += a1 * w1.z; acc[1][7] += a1 * w1.w;
    }

    float4 bb0 = *(const float4*)(bias + tx * 4);
    float4 bb1 = *(const float4*)(bias + 64 + tx * 4);
    #pragma unroll
    for (int i = 0; i < 2; i++) {
        int row = row0 + ty * 2 + i;
        if (row < N) {
            ushort4 h0, h1;
            h0.x = f2h(acc[i][0] + bb0.x); h0.y = f2h(acc[i][1] + bb0.y);
            h0.z = f2h(acc[i][2] + bb0.z); h0.w = f2h(acc[i][3] + bb0.w);
            h1.x = f2h(acc[i][4] + bb1.x); h1.y = f2h(acc[i][5] + bb1.y);
            h1.z = f2h(acc[i][6] + bb1.z); h1.w = f2h(acc[i][7] + bb1.w);
            *(ushort4*)(outp + (size_t)row * HID + tx * 4) = h0;
            *(ushort4*)(outp + (size_t)row * HID + 64 + tx * 4) = h1;
        }
    }
}

// ---------------------------------------------------------------- layer-1 combine: Hb = fp16(elu(att(fp16) + x@W + b))
__global__ __launch_bounds__(256) void combine16_kernel(
    const float* __restrict__ Hin,
    const float* __restrict__ W, const float* __restrict__ bias,
    const unsigned short* __restrict__ Att, unsigned short* __restrict__ Hb,
    int N) {
    constexpr int K = 16;
    __shared__ float Ws[K][HID];
    __shared__ float Hs[32][K + 4];

    int row0 = blockIdx.x * 32;
    int tid = threadIdx.x;
    int tx = tid & 15, ty = tid >> 4;

    for (int i = tid; i < 32 * (K / 4); i += 256) {
        int r = i / (K / 4), kq = i % (K / 4);
        int row = row0 + r;
        float4 v = make_float4(0.f, 0.f, 0.f, 0.f);
        if (row < N) v = *(const float4*)(Hin + (size_t)row * K + kq * 4);
        *(float4*)&Hs[r][kq * 4] = v;
    }
    for (int i = tid; i < K * 32; i += 256) {
        int k = i >> 5, cq = i & 31;
        *(float4*)&Ws[k][cq * 4] = *(const float4*)(W + (size_t)k * HID + cq * 4);
    }
    __syncthreads();

    float acc[2][8];
    #pragma unroll
    for (int i = 0; i < 2; i++)
        #pragma unroll
        for (int j = 0; j < 8; j++) acc[i][j] = 0.f;

    int r0 = ty * 2, r1 = ty * 2 + 1;
    #pragma unroll
    for (int k = 0; k < K; k++) {
        float a0 = Hs[r0][k];
        float a1 = Hs[r1][k];
        float4 w0 = *(float4*)&Ws[k][tx * 4];
        float4 w1 = *(float4*)&Ws[k][64 + tx * 4];
        acc[0][0] += a0 * w0.x; acc[0][1] += a0 * w0.y; acc[0][2] += a0 * w0.z; acc[0][3] += a0 * w0.w;
        acc[0][4] += a0 * w1.x; acc[0][5] += a0 * w1.y; acc[0][6] += a0 * w1.z; acc[0][7] += a0 * w1.w;
        acc[1][0] += a1 * w0.x; acc[1][1] += a1 * w0.y; acc[1][2] += a1 * w0.z; acc[1][3] += a1 * w0.w;
        acc[1][4] += a1 * w1.x; acc[1][5] += a1 * w1.y; acc[1][6] += a1 * w1.z; acc[1][7] += a1 * w1.w;
    }

    float4 bb0 = *(const float4*)(bias + tx * 4);
    float4 bb1 = *(const float4*)(bias + 64 + tx * 4);
    #pragma unroll
    for (int i = 0; i < 2; i++) {
        int row = row0 + ty * 2 + i;
        if (row < N) {
            const unsigned short* p0 = Att + (size_t)row * HID + tx * 4;
            ushort4 g0 = *(const ushort4*)p0;
            ushort4 g1 = *(const ushort4*)(p0 + 64);
            float v[8];
            v[0] = h2f(g0.x) + acc[i][0] + bb0.x; v[1] = h2f(g0.y) + acc[i][1] + bb0.y;
            v[2] = h2f(g0.z) + acc[i][2] + bb0.z; v[3] = h2f(g0.w) + acc[i][3] + bb0.w;
            v[4] = h2f(g1.x) + acc[i][4] + bb1.x; v[5] = h2f(g1.y) + acc[i][5] + bb1.y;
            v[6] = h2f(g1.z) + acc[i][6] + bb1.z; v[7] = h2f(g1.w) + acc[i][7] + bb1.w;
            #pragma unroll
            for (int j = 0; j < 8; j++) v[j] = (v[j] > 0.f) ? v[j] : (__expf(v[j]) - 1.f);
            ushort4 h0, h1;
            h0.x = f2h(v[0]); h0.y = f2h(v[1]); h0.z = f2h(v[2]); h0.w = f2h(v[3]);
            h1.x = f2h(v[4]); h1.y = f2h(v[5]); h1.z = f2h(v[6]); h1.w = f2h(v[7]);
            *(ushort4*)(Hb + (size_t)row * HID + tx * 4) = h0;
            *(ushort4*)(Hb + (size_t)row * HID + 64 + tx * 4) = h1;
        }
    }
}

// ---------------------------------------------------------------- edge: packed _Float16 vector math.
// ONE node/wave; halves split edge list; no running max (logits O(1), clamp 60); plain-sum accumulators.
// FUSE=0 (layer 1): output att+gbias as fp16 -> hb.  FUSE=1: +lin, elu, fp16 -> hb (+f32 hf if non-null).
template <int FUSE>
__global__ __launch_bounds__(256) void edgeh_kernel(
    const unsigned short* __restrict__ XL, const unsigned short* __restrict__ XR,
    const int* __restrict__ row_ptr, const int* __restrict__ csr_src,
    const unsigned int* __restrict__ csr_eap,
    const float* __restrict__ att,
    const float* __restrict__ We,
    const float* __restrict__ gbias,
    const unsigned short* __restrict__ lin,
    float* __restrict__ hf, unsigned short* __restrict__ hb,
    int N) {
    int n = (blockIdx.x * 256 + threadIdx.x) >> 6;
    int lane = threadIdx.x & 63;
    int half = lane >> 5;
    int l = lane & 31;
    bool active = (n < N);
    int nn = active ? n : 0;

    int c0 = l * 4;
    float4 avf = *(const float4*)(att + c0);
    float4 w0f = *(const float4*)(We + c0);
    float4 w1f = *(const float4*)(We + HID + c0);
    h2v avA; avA[0] = (_Float16)avf.x; avA[1] = (_Float16)avf.y;
    h2v avB; avB[0] = (_Float16)avf.z; avB[1] = (_Float16)avf.w;
    h2v weA0; weA0[0] = (_Float16)w0f.x; weA0[1] = (_Float16)w0f.y;
    h2v weB0; weB0[0] = (_Float16)w0f.z; weB0[1] = (_Float16)w0f.w;
    h2v weA1; weA1[0] = (_Float16)w1f.x; weA1[1] = (_Float16)w1f.y;
    h2v weB1; weB1[0] = (_Float16)w1f.z; weB1[1] = (_Float16)w1f.w;
    h2v k02; k02[0] = (_Float16)0.2f; k02[1] = (_Float16)0.2f;

    ushort4 xru = *(const ushort4*)(XR + (size_t)nn * HID + c0);
    h2v xrA = mkh2(xru.x, xru.y), xrB = mkh2(xru.z, xru.w);

    int eb = 0, eend = 0;
    if (active) { eb = row_ptr[n]; eend = row_ptr[n + 1]; }
    int mid = (eb + eend + 1) >> 1;
    int sb = half ? mid : eb;
    int se = half ? eend : mid;

    float l_run = 0.f;
    float4 fa = make_float4(0.f, 0.f, 0.f, 0.f);

    for (int base = sb; base < se; base += 32) {
        int cnt = min(32, se - base);
        int myi = base + l;
        int msrc = 0; unsigned mea = 0;
        if (myi < se) { msrc = csr_src[myi]; mea = csr_eap[myi]; }

        int s0 = __shfl(msrc, 0, 32);
        int s1 = __shfl(msrc, 1, 32);
        unsigned e0 = __shfl(mea, 0, 32);
        unsigned e1 = __shfl(mea, 1, 32);
        ushort4 u0 = *(const ushort4*)(XL + (size_t)s0 * HID + c0);
        ushort4 u1 = *(const ushort4*)(XL + (size_t)s1 * HID + c0);

        for (int j = 0; ; j += 2) {
            bool more = (j + 2 < cnt);
            int ns0 = 0, ns1 = 0; unsigned ne0 = 0, ne1 = 0;
            ushort4 nu0, nu1;
            if (more) {
                ns0 = __shfl(msrc, j + 2, 32);
                ns1 = __shfl(msrc, j + 3, 32);
                ne0 = __shfl(mea, j + 2, 32);
                ne1 = __shfl(mea, j + 3, 32);
                nu0 = *(const ushort4*)(XL + (size_t)ns0 * HID + c0);
                nu1 = *(const ushort4*)(XL + (size_t)ns1 * HID + c0);
            }
            h2v ex0 = splath((unsigned short)(e0 & 0xffff));
            h2v ey0 = splath((unsigned short)(e0 >> 16));
            h2v ex1 = splath((unsigned short)(e1 & 0xffff));
            h2v ey1 = splath((unsigned short)(e1 >> 16));
            h2v xl0A = mkh2(u0.x, u0.y), xl0B = mkh2(u0.z, u0.w);
            h2v xl1A = mkh2(u1.x, u1.y), xl1B = mkh2(u1.z, u1.w);

            h2v mA = xl0A + xrA + ex0 * weA0 + ey0 * weA1;
            mA = __builtin_elementwise_max(mA, k02 * mA);
            h2v mB = xl0B + xrB + ex0 * weB0 + ey0 * weB1;
            mB = __builtin_elementwise_max(mB, k02 * mB);
            float part0 = fdot2v(mB, avB, fdot2v(mA, avA, 0.f));

            h2v nA = xl1A + xrA + ex1 * weA0 + ey1 * weA1;
            nA = __builtin_elementwise_max(nA, k02 * nA);
            h2v nB = xl1B + xrB + ex1 * weB0 + ey1 * weB1;
            nB = __builtin_elementwise_max(nB, k02 * nB);
            float part1 = fdot2v(nB, avB, fdot2v(nA, avA, 0.f));

            float t;
            t = __shfl_xor(part0, 1); part0 += t;
            t = __shfl_xor(part0, 2); part0 += t;
            t = __shfl_xor(part1, 1); part1 += t;
            t = __shfl_xor(part1, 2); part1 += t;

            bool two = (j + 1 < cnt);
            float p0 = __expf(fminf(part0, 60.f));
            float p1 = two ? __expf(fminf(part1, 60.f)) : 0.f;
            l_run += p0 + p1;
            fa.x += p0 * h2f(u0.x) + p1 * h2f(u1.x);
            fa.y += p0 * h2f(u0.y) + p1 * h2f(u1.y);
            fa.z += p0 * h2f(u0.z) + p1 * h2f(u1.z);
            fa.w += p0 * h2f(u0.w) + p1 * h2f(u1.w);
            if (!more) break;
            s0 = ns0; s1 = ns1; e0 = ne0; e1 = ne1; u0 = nu0; u1 = nu1;
        }
    }

    l_run += __shfl_xor(l_run, 32);
    fa.x += __shfl_xor(fa.x, 32);
    fa.y += __shfl_xor(fa.y, 32);
    fa.z += __shfl_xor(fa.z, 32);
    fa.w += __shfl_xor(fa.w, 32);

    if (!active || half) return;
    float inv = 1.f / fmaxf(l_run, 1e-16f);
    float4 bias4 = *(const float4*)(gbias + c0);
    float4 v;
    v.x = fa.x * inv + bias4.x;
    v.y = fa.y * inv + bias4.y;
    v.z = fa.z * inv + bias4.z;
    v.w = fa.w * inv + bias4.w;
    if constexpr (FUSE) {
        ushort4 lu = *(const ushort4*)(lin + (size_t)n * HID + c0);
        v.x += h2f(lu.x); v.y += h2f(lu.y); v.z += h2f(lu.z); v.w += h2f(lu.w);
        v.x = (v.x > 0.f) ? v.x : (__expf(v.x) - 1.f);
        v.y = (v.y > 0.f) ? v.y : (__expf(v.y) - 1.f);
        v.z = (v.z > 0.f) ? v.z : (__expf(v.z) - 1.f);
        v.w = (v.w > 0.f) ? v.w : (__expf(v.w) - 1.f);
        if (hf) *(float4*)(hf + (size_t)n * HID + c0) = v;
    }
    ushort4 hh;
    hh.x = f2h(v.x); hh.y = f2h(v.y); hh.z = f2h(v.z); hh.w = f2h(v.w);
    *(ushort4*)(hb + (size_t)n * HID + c0) = hh;
}

// ---------------------------------------------------------------- mean pool per graph
__global__ __launch_bounds__(128) void pool_kernel(const float* __restrict__ h,
                                                   const int* __restrict__ batch,
                                                   float* __restrict__ g, int N) {
    int gid = blockIdx.x;
    int lo = lower_bound_i(batch, N, gid);
    int hi = lower_bound_i(batch, N, gid + 1);
    int c = threadIdx.x;
    float s = 0.f;
    for (int i = lo; i < hi; i++) s += h[(size_t)i * HID + c];
    g[gid * HID + c] = s / fmaxf((float)(hi - lo), 1.0f);
}

// ---------------------------------------------------------------- readout GEMM
__global__ __launch_bounds__(256) void readout_kernel(const float* __restrict__ g,
                                                      const float* __restrict__ W,
                                                      const float* __restrict__ b,
                                                      float* __restrict__ out, int S) {
    __shared__ float gs[HID];
    int gid = blockIdx.y;
    if (threadIdx.x < HID) gs[threadIdx.x] = g[gid * HID + threadIdx.x];
    __syncthreads();
    int c = blockIdx.x * 256 + threadIdx.x;
    if (c < S) {
        float acc = b[c];
        #pragma unroll 8
        for (int k = 0; k < HID; k++) acc += gs[k] * W[(size_t)k * S + c];
        out[(size_t)gid * S + c] = acc;
    }
}

// ---------------------------------------------------------------- launcher
extern "C" void kernel_launch(void* const* d_in, const int* in_sizes, int n_in,
                              void* d_out, int out_size, void* d_ws, size_t ws_size,
                              hipStream_t stream) {
    const float* x      = (const float*)d_in[0];
    const int*   ei     = (const int*)d_in[1];
    const float* eattr  = (const float*)d_in[2];
    const int*   batch  = (const int*)d_in[3];
    const float* at1_Wl = (const float*)d_in[4];
    const float* at1_bl = (const float*)d_in[5];
    const float* at1_Wr = (const float*)d_in[6];
    const float* at1_br = (const float*)d_in[7];
    const float* at1_We = (const float*)d_in[8];
    const float* at1_att= (const float*)d_in[9];
    const float* at1_b  = (const float*)d_in[10];
    const float* l1_W   = (const float*)d_in[11];
    const float* l1_b   = (const float*)d_in[12];
    const float* atk_Wl = (const float*)d_in[13];
    const float* atk_bl = (const float*)d_in[14];
    const float* atk_Wr = (const float*)d_in[15];
    const float* atk_br = (const float*)d_in[16];
    const float* atk_We = (const float*)d_in[17];
    const float* atk_att= (const float*)d_in[18];
    const float* atk_b  = (const float*)d_in[19];
    const float* lk_W   = (const float*)d_in[20];
    const float* lk_b   = (const float*)d_in[21];
    const float* lin_W  = (const float*)d_in[22];
    const float* lin_b  = (const float*)d_in[23];
    float* out = (float*)d_out;

    const int N  = in_sizes[0] / 16;
    const int E  = in_sizes[1] / 2;
    const int ET = E + N;
    const int S  = 1000;
    const int G  = out_size / S;

    char* w = (char*)d_ws;
    auto alloc = [&](size_t bytes) -> char* {
        char* p = w; w += (bytes + 255) & ~(size_t)255; return p;
    };
    unsigned short* XLb = (unsigned short*)alloc((size_t)N * HID * 2);
    unsigned short* XRb = (unsigned short*)alloc((size_t)N * HID * 2);
    unsigned short* Linb = (unsigned short*)alloc((size_t)N * HID * 2);   // also layer-1 Att buffer
    float*  Hf      = (float*)alloc((size_t)N * HID * 4);
    unsigned short* Hb = (unsigned short*)alloc((size_t)N * HID * 2);
    int*    deg     = (int*)alloc((size_t)N * 4);
    int*    row_ptr = (int*)alloc((size_t)(N + 1) * 4);
    int*    cursor  = (int*)alloc((size_t)N * 4);
    int*    csr_src = (int*)alloc((size_t)ET * 4);
    unsigned int* csr_eap = (unsigned int*)alloc((size_t)ET * 4);
    float*  meansum = (float*)alloc(8);
    int*    bsum    = (int*)alloc(256);
    int*    boff    = (int*)alloc(256);
    unsigned short* WlTh = (unsigned short*)alloc((size_t)9 * 16384 * 2);
    unsigned short* WrTh = (unsigned short*)alloc((size_t)9 * 16384 * 2);
    unsigned short* WkTh = (unsigned short*)alloc((size_t)9 * 16384 * 2);
    float*  gpool   = (float*)alloc((size_t)G * HID * 4);
    (void)ws_size; (void)n_in;

    hipError_t err;
    err = hipMemsetAsync(deg, 0, (size_t)N * 4, stream); (void)err;
    err = hipMemsetAsync(meansum, 0, 8, stream); (void)err;

    const int wtot = 9 * 16384;
    wprep_kernel<<<dim3((wtot + 255) / 256, 3), 256, 0, stream>>>(atk_Wl, atk_Wr, lk_W,
                                                                  WlTh, WrTh, WkTh, wtot);

    mean_kernel<<<256, 256, 0, stream>>>(eattr, meansum, E);
    deg_kernel<<<(ET + 255) / 256, 256, 0, stream>>>(ei, deg, E, ET);
    const int NB = (N + 1023) / 1024;
    scanA_kernel<<<NB, 256, 0, stream>>>(deg, bsum, N);
    scanB_kernel<<<1, 64, 0, stream>>>(bsum, boff, row_ptr, NB, N);
    scanC_kernel<<<NB, 256, 0, stream>>>(deg, boff, row_ptr, cursor, N);
    fill_kernel<<<(ET + 255) / 256, 256, 0, stream>>>(ei, eattr, meansum, cursor, csr_src, csr_eap, E, ET);

    const int gx16 = (N + 31) / 32;
    const int ge   = (N + 3) / 4;
    const int gx3  = (N + 63) / 64;

    transform16_kernel<<<dim3(gx16, 1, 2), 256, 0, stream>>>(x, at1_Wl, at1_bl, XLb, at1_Wr, at1_br, XRb, N);
    edgeh_kernel<0><<<ge, 256, 0, stream>>>(XLb, XRb, row_ptr, csr_src, csr_eap, at1_att, at1_We, at1_b,
                                            nullptr, nullptr, Linb, N);
    combine16_kernel<<<gx16, 256, 0, stream>>>(x, l1_W, l1_b, Linb, Hb, N);

    for (int i = 0; i < 9; i++) {
        const unsigned short* wlh = WlTh + (size_t)i * 16384;
        const unsigned short* wrh = WrTh + (size_t)i * 16384;
        const unsigned short* wkh = WkTh + (size_t)i * 16384;
        const float* bl = atk_bl + (size_t)i * HID;
        const float* br = atk_br + (size_t)i * HID;
        const float* bk = lk_b   + (size_t)i * HID;
        const float* Wep = atk_We + (size_t)i * 2 * HID;
        const float* at = atk_att + (size_t)i * HID;
        const float* ab = atk_b  + (size_t)i * HID;

        gemm3_kernel<<<gx3, 256, 0, stream>>>(Hb,
                                              wlh, bl, XLb,
                                              wrh, br, XRb,
                                              wkh, bk, Linb, N);
        edgeh_kernel<1><<<ge, 256, 0, stream>>>(XLb, XRb, row_ptr, csr_src, csr_eap, at, Wep, ab,
                                                Linb, (i == 8) ? Hf : nullptr, Hb, N);
    }

    pool_kernel<<<G, 128, 0, stream>>>(Hf, batch, gpool, N);
    readout_kernel<<<dim3((S + 255) / 256, G), 256, 0, stream>>>(gpool, lin_W, lin_b, out, S);
}

// Round 17
// 692.661 us; speedup vs baseline: 1.1803x; 1.0057x over previous
//
#include <hip/hip_runtime.h>
#include <hip/hip_fp16.h>
#include <cstdint>

#define HID 128

typedef __attribute__((ext_vector_type(8))) _Float16 f16x8;
typedef __attribute__((ext_vector_type(2))) _Float16 h2v;
typedef __attribute__((ext_vector_type(4))) float f32x4;

__device__ __forceinline__ unsigned short f2h(float x) {
    return __builtin_bit_cast(unsigned short, (_Float16)x);
}
__device__ __forceinline__ float h2f(unsigned short u) {
    return (float)__builtin_bit_cast(_Float16, u);
}
__device__ __forceinline__ h2v mkh2(unsigned short a, unsigned short b) {
    unsigned v = (unsigned)a | ((unsigned)b << 16);
    return __builtin_bit_cast(h2v, v);
}
__device__ __forceinline__ h2v splath(unsigned short a) {
    _Float16 h = __builtin_bit_cast(_Float16, a);
    h2v r; r[0] = h; r[1] = h;
    return r;
}
__device__ __forceinline__ float fdot2v(h2v a, h2v b, float c) {
    return __builtin_amdgcn_fdot2(a, b, c, false);
}
__device__ __forceinline__ int lower_bound_i(const int* a, int n, int v) {
    int lo = 0, hi = n;
    while (lo < hi) { int m = (lo + hi) >> 1; if (a[m] < v) lo = m + 1; else hi = m; }
    return lo;
}

// ---------------------------------------------------------------- mean of edge_attr (256 grid-stride blocks:
// only 1024 wave-atomics to the two meansum addresses -- single-address float atomics serialize, keep count low)
__global__ __launch_bounds__(256) void mean_kernel(const float* __restrict__ eattr,
                                                   float* __restrict__ meansum, int E) {
    float sx = 0.f, sy = 0.f;
    for (int i = blockIdx.x * 256 + threadIdx.x; i < E; i += gridDim.x * 256) {
        float2 v = *(const float2*)(eattr + 2 * (size_t)i);
        sx += v.x; sy += v.y;
    }
    for (int d = 1; d < 64; d <<= 1) { sx += __shfl_xor(sx, d); sy += __shfl_xor(sy, d); }
    if ((threadIdx.x & 63) == 0) { atomicAdd(&meansum[0], sx); atomicAdd(&meansum[1], sy); }
}

// ---------------------------------------------------------------- CSR build
__global__ __launch_bounds__(256) void deg_kernel(const int* __restrict__ ei,
                                                  int* __restrict__ deg, int E, int ET) {
    int e = blockIdx.x * 256 + threadIdx.x;
    if (e >= ET) return;
    int dst = (e < E) ? ei[E + e] : (e - E);
    atomicAdd(&deg[dst], 1);
}

__global__ __launch_bounds__(256) void scanA_kernel(const int* __restrict__ deg,
                                                    int* __restrict__ bsum, int N) {
    __shared__ int ws[4];
    int t = threadIdx.x;
    int base = blockIdx.x * 1024 + t * 4;
    int s = 0;
    #pragma unroll
    for (int j = 0; j < 4; j++) { int idx = base + j; if (idx < N) s += deg[idx]; }
    for (int d = 1; d < 64; d <<= 1) s += __shfl_xor(s, d);
    if ((t & 63) == 0) ws[t >> 6] = s;
    __syncthreads();
    if (t == 0) bsum[blockIdx.x] = ws[0] + ws[1] + ws[2] + ws[3];
}

__global__ __launch_bounds__(64) void scanB_kernel(const int* __restrict__ bsum,
                                                   int* __restrict__ boff,
                                                   int* __restrict__ row_ptr, int NB, int N) {
    int t = threadIdx.x;
    int v = (t < NB) ? bsum[t] : 0;
    int inc = v;
    #pragma unroll
    for (int d = 1; d < 64; d <<= 1) { int u = __shfl_up(inc, d); if (t >= d) inc += u; }
    if (t < NB) boff[t] = inc - v;
    if (t == 63) row_ptr[N] = inc;
}

__global__ __launch_bounds__(256) void scanC_kernel(const int* __restrict__ deg,
                                                    const int* __restrict__ boff,
                                                    int* __restrict__ row_ptr,
                                                    int* __restrict__ cursor, int N) {
    __shared__ int wsum[4];
    int t = threadIdx.x;
    int lane = t & 63, wid = t >> 6;
    int base = blockIdx.x * 1024 + t * 4;
    int v[4]; int s = 0;
    #pragma unroll
    for (int j = 0; j < 4; j++) { int idx = base + j; v[j] = (idx < N) ? deg[idx] : 0; s += v[j]; }
    int inc = s;
    #pragma unroll
    for (int d = 1; d < 64; d <<= 1) { int u = __shfl_up(inc, d); if (lane >= d) inc += u; }
    if (lane == 63) wsum[wid] = inc;
    __syncthreads();
    int woff = 0;
    for (int ww = 0; ww < wid; ww++) woff += wsum[ww];
    int excl = boff[blockIdx.x] + woff + inc - s;
    #pragma unroll
    for (int j = 0; j < 4; j++) {
        int idx = base + j;
        if (idx < N) { row_ptr[idx] = excl; cursor[idx] = excl; }
        excl += v[j];
    }
}

__global__ __launch_bounds__(256) void fill_kernel(const int* __restrict__ ei,
                                                   const float* __restrict__ eattr,
                                                   const float* __restrict__ meansum,
                                                   int* __restrict__ cursor,
                                                   int* __restrict__ csr_src,
                                                   unsigned int* __restrict__ csr_eap,
                                                   int E, int ET) {
    int e = blockIdx.x * 256 + threadIdx.x;
    if (e >= ET) return;
    int src, dst; float2 ea;
    if (e < E) {
        src = ei[e]; dst = ei[E + e];
        ea = *(const float2*)(eattr + 2 * (size_t)e);
    } else {
        src = dst = e - E;
        float inv = 1.0f / (float)E;
        ea.x = meansum[0] * inv; ea.y = meansum[1] * inv;
    }
    unsigned pea = (unsigned)f2h(ea.x) | ((unsigned)f2h(ea.y) << 16);   // fp16 pair
    int pos = atomicAdd(&cursor[dst], 1);
    csr_src[pos] = src;
    csr_eap[pos] = pea;
}

// ---------------------------------------------------------------- weight prep: 3 matrices in one dispatch
__global__ __launch_bounds__(256) void wprep_kernel(const float* __restrict__ s0,
                                                    const float* __restrict__ s1,
                                                    const float* __restrict__ s2,
                                                    unsigned short* __restrict__ d0,
                                                    unsigned short* __restrict__ d1,
                                                    unsigned short* __restrict__ d2, int total) {
    int y = blockIdx.y;
    const float* src = (y == 0) ? s0 : (y == 1) ? s1 : s2;
    unsigned short* dst = (y == 0) ? d0 : (y == 1) ? d1 : d2;
    int idx = blockIdx.x * 256 + threadIdx.x;
    if (idx >= total) return;
    int layer = idx >> 14;
    int rem = idx & 16383;
    int n = rem >> 7, k = rem & 127;
    dst[idx] = f2h(src[(layer << 14) | (k << 7) | n]);
}

// ---------------------------------------------------------------- 3-GEMM sequential: A(fp16) loaded ONCE, W(fp16)
// staged per-matrix in LDS; 64-row blocks; swapped operands -> packed ushort4 stores (fp16).
#define LROW 136
__global__ __launch_bounds__(256) void gemm3_kernel(
    const unsigned short* __restrict__ Hb,
    const unsigned short* __restrict__ W0h, const float* __restrict__ b0, unsigned short* __restrict__ o0,
    const unsigned short* __restrict__ W1h, const float* __restrict__ b1, unsigned short* __restrict__ o1,
    const unsigned short* __restrict__ W2h, const float* __restrict__ b2, unsigned short* __restrict__ o2,
    int N) {
    __shared__ unsigned short lds_h[128 * LROW];
    int tid = threadIdx.x;
    int wid = tid >> 6, lane = tid & 63;
    int row0 = blockIdx.x * 64 + wid * 16;
    int lr = lane & 15;
    int cgrp = lane >> 4;
    int kb = cgrp * 8;
    bool rowsok = (row0 < N);

    f16x8 ha[4];
    {
        int node = row0 + lr;
        int nodec = rowsok ? ((node < N) ? node : (N - 1)) : 0;
        const unsigned short* pa = Hb + (size_t)nodec * HID + kb;
        #pragma unroll
        for (int kf = 0; kf < 4; kf++) ha[kf] = *(const f16x8*)(pa + kf * 32);
    }

    const unsigned short* Whs[3] = {W0h, W1h, W2h};
    const float* Bs[3] = {b0, b1, b2};
    unsigned short* Os[3] = {o0, o1, o2};

    for (int w = 0; w < 3; w++) {
        if (w) __syncthreads();
        const unsigned short* sh = Whs[w];
        #pragma unroll
        for (int j = 0; j < 8; j++) {
            int c = tid + 256 * j;
            int r = c >> 4, col = (c & 15) * 8;
            *(f16x8*)&lds_h[r * LROW + col] = *(const f16x8*)(sh + r * HID + col);
        }
        __syncthreads();
        if (!rowsok) continue;

        const float* bias = Bs[w];
        unsigned short* outp = Os[w];
        #pragma unroll 2
        for (int nf = 0; nf < 8; nf++) {
            int wrow = nf * 16 + lr;
            const unsigned short* ph = &lds_h[wrow * LROW + kb];
            f16x8 wf[4];
            #pragma unroll
            for (int kf = 0; kf < 4; kf++) wf[kf] = *(const f16x8*)(ph + kf * 32);
            f32x4 acc = {0.f, 0.f, 0.f, 0.f};
            #pragma unroll
            for (int kf = 0; kf < 4; kf++)
                acc = __builtin_amdgcn_mfma_f32_16x16x32_f16(wf[kf], ha[kf], acc, 0, 0, 0);
            int chb = nf * 16 + cgrp * 4;
            float4 bias4 = *(const float4*)(bias + chb);
            int node = row0 + lr;
            ushort4 u;
            u.x = f2h(acc[0] + bias4.x); u.y = f2h(acc[1] + bias4.y);
            u.z = f2h(acc[2] + bias4.z); u.w = f2h(acc[3] + bias4.w);
            if (node < N) *(ushort4*)(outp + (size_t)node * HID + chb) = u;
        }
    }
}

// ---------------------------------------------------------------- layer-1 transform (K=16, f32 in -> fp16 out)
__global__ __launch_bounds__(256) void transform16_kernel(
    const float* __restrict__ Hin,
    const float* __restrict__ W0, const float* __restrict__ b0, unsigned short* __restrict__ o0,
    const float* __restrict__ W1, const float* __restrict__ b1, unsigned short* __restrict__ o1,
    int N) {
    constexpr int K = 16;
    __shared__ float Ws[K][HID];
    __shared__ float Hs[32][K + 4];

    const float* W; const float* bias; unsigned short* outp;
    if (blockIdx.z == 0) { W = W0; bias = b0; outp = o0; }
    else                 { W = W1; bias = b1; outp = o1; }

    int row0 = blockIdx.x * 32;
    int tid = threadIdx.x;
    int tx = tid & 15, ty = tid >> 4;

    for (int i = tid; i < 32 * (K / 4); i += 256) {
        int r = i / (K / 4), kq = i % (K / 4);
        int row = row0 + r;
        float4 v = make_float4(0.f, 0.f, 0.f, 0.f);
        if (row < N) v = *(const float4*)(Hin + (size_t)row * K + kq * 4);
        *(float4*)&Hs[r][kq * 4] = v;
    }
    for (int i = tid; i < K * 32; i += 256) {
        int k = i >> 5, cq = i & 31;
        *(float4*)&Ws[k][cq * 4] = *(const float4*)(W + (size_t)k * HID + cq * 4);
    }
    __syncthreads();

    float acc[2][8];
    #pragma unroll
    for (int i = 0; i < 2; i++)
        #pragma unroll
        for (int j = 0; j < 8; j++) acc[i][j] = 0.f;

    int r0 = ty * 2, r1 = ty * 2 + 1;
    #pragma unroll
    for (int k = 0; k < K; k++) {
        float a0 = Hs[r0][k];
        float a1 = Hs[r1][k];
        float4 w0 = *(float4*)&Ws[k][tx * 4];
        float4 w1 = *(float4*)&Ws[k][64 + tx * 4];
        acc[0][0] += a0 * w0.x; acc[0][1] += a0 * w0.y; acc[0][2] += a0 * w0.z; acc[0][3] += a0 * w0.w;
        acc[0][4] += a0 * w1.x; acc[0][5] += a0 * w1.y; acc[0][6] += a0 * w1.z; acc[0][7] += a0 * w1.w;
        acc[1][0] += a1 * w0.x; acc[1][1] += a1 * w0.y; acc[1][2] += a1 * w0.z; acc[1][3] += a1 * w0.w;
        acc[1][4] += a1 * w1.x; acc[1][5] += a1 * w1.y; acc[1][6] += a1 * w1.z; acc[1][7] += a1 * w1.w;
    }

    float4 bb0 = *(const float4*)(bias + tx * 4);
    float4 bb1 = *(const float4*)(bias + 64 + tx * 4);
    #pragma unroll
    for (int i = 0; i < 2; i++) {
        int row = row0 + ty * 2 + i;
        if (row < N) {
            ushort4 h0, h1;
            h0.x = f2h(acc[i][0] + bb0.x); h0.y = f2h(acc[i][1] + bb0.y);
            h0.z = f2h(acc[i][2] + bb0.z); h0.w = f2h(acc[i][3] + bb0.w);
            h1.x = f2h(acc[i][4] + bb1.x); h1.y = f2h(acc[i][5] + bb1.y);
            h1.z = f2h(acc[i][6] + bb1.z); h1.w = f2h(acc[i][7] + bb1.w);
            *(ushort4*)(outp + (size_t)row * HID + tx * 4) = h0;
            *(ushort4*)(outp + (size_t)row * HID + 64 + tx * 4) = h1;
        }
    }
}

// ---------------------------------------------------------------- layer-1 combine: Hb = fp16(elu(att(fp16) + x@W + b))
__global__ __launch_bounds__(256) void combine16_kernel(
    const float* __restrict__ Hin,
    const float* __restrict__ W, const float* __restrict__ bias,
    const unsigned short* __restrict__ Att, unsigned short* __restrict__ Hb,
    int N) {
    constexpr int K = 16;
    __shared__ float Ws[K][HID];
    __shared__ float Hs[32][K + 4];

    int row0 = blockIdx.x * 32;
    int tid = threadIdx.x;
    int tx = tid & 15, ty = tid >> 4;

    for (int i = tid; i < 32 * (K / 4); i += 256) {
        int r = i / (K / 4), kq = i % (K / 4);
        int row = row0 + r;
        float4 v = make_float4(0.f, 0.f, 0.f, 0.f);
        if (row < N) v = *(const float4*)(Hin + (size_t)row * K + kq * 4);
        *(float4*)&Hs[r][kq * 4] = v;
    }
    for (int i = tid; i < K * 32; i += 256) {
        int k = i >> 5, cq = i & 31;
        *(float4*)&Ws[k][cq * 4] = *(const float4*)(W + (size_t)k * HID + cq * 4);
    }
    __syncthreads();

    float acc[2][8];
    #pragma unroll
    for (int i = 0; i < 2; i++)
        #pragma unroll
        for (int j = 0; j < 8; j++) acc[i][j] = 0.f;

    int r0 = ty * 2, r1 = ty * 2 + 1;
    #pragma unroll
    for (int k = 0; k < K; k++) {
        float a0 = Hs[r0][k];
        float a1 = Hs[r1][k];
        float4 w0 = *(float4*)&Ws[k][tx * 4];
        float4 w1 = *(float4*)&Ws[k][64 + tx * 4];
        acc[0][0] += a0 * w0.x; acc[0][1] += a0 * w0.y; acc[0][2] += a0 * w0.z; acc[0][3] += a0 * w0.w;
        acc[0][4] += a0 * w1.x; acc[0][5] += a0 * w1.y; acc[0][6] += a0 * w1.z; acc[0][7] += a0 * w1.w;
        acc[1][0] += a1 * w0.x; acc[1][1] += a1 * w0.y; acc[1][2] += a1 * w0.z; acc[1][3] += a1 * w0.w;
        acc[1][4] += a1 * w1.x; acc[1][5] += a1 * w1.y; acc[1][6] += a1 * w1.z; acc[1][7] += a1 * w1.w;
    }

    float4 bb0 = *(const float4*)(bias + tx * 4);
    float4 bb1 = *(const float4*)(bias + 64 + tx * 4);
    #pragma unroll
    for (int i = 0; i < 2; i++) {
        int row = row0 + ty * 2 + i;
        if (row < N) {
            const unsigned short* p0 = Att + (size_t)row * HID + tx * 4;
            ushort4 g0 = *(const ushort4*)p0;
            ushort4 g1 = *(const ushort4*)(p0 + 64);
            float v[8];
            v[0] = h2f(g0.x) + acc[i][0] + bb0.x; v[1] = h2f(g0.y) + acc[i][1] + bb0.y;
            v[2] = h2f(g0.z) + acc[i][2] + bb0.z; v[3] = h2f(g0.w) + acc[i][3] + bb0.w;
            v[4] = h2f(g1.x) + acc[i][4] + bb1.x; v[5] = h2f(g1.y) + acc[i][5] + bb1.y;
            v[6] = h2f(g1.z) + acc[i][6] + bb1.z; v[7] = h2f(g1.w) + acc[i][7] + bb1.w;
            #pragma unroll
            for (int j = 0; j < 8; j++) v[j] = (v[j] > 0.f) ? v[j] : (__expf(v[j]) - 1.f);
            ushort4 h0, h1;
            h0.x = f2h(v[0]); h0.y = f2h(v[1]); h0.z = f2h(v[2]); h0.w = f2h(v[3]);
            h1.x = f2h(v[4]); h1.y = f2h(v[5]); h1.z = f2h(v[6]); h1.w = f2h(v[7]);
            *(ushort4*)(Hb + (size_t)row * HID + tx * 4) = h0;
            *(ushort4*)(Hb + (size_t)row * HID + 64 + tx * 4) = h1;
        }
    }
}

// ---------------------------------------------------------------- edge: packed _Float16 vector math.
// ONE node/wave (512-thread blocks = 8 waves); halves split edge list; no running max; plain-sum accumulators.
// FUSE=0 (layer 1): att+gbias -> fp16 hb.  FUSE=1: +lin, elu -> fp16 hb.
template <int FUSE>
__global__ __launch_bounds__(512) void edgeh_kernel(
    const unsigned short* __restrict__ XL, const unsigned short* __restrict__ XR,
    const int* __restrict__ row_ptr, const int* __restrict__ csr_src,
    const unsigned int* __restrict__ csr_eap,
    const float* __restrict__ att,
    const float* __restrict__ We,
    const float* __restrict__ gbias,
    const unsigned short* __restrict__ lin,
    unsigned short* __restrict__ hb,
    int N) {
    int n = (blockIdx.x * 512 + threadIdx.x) >> 6;
    int lane = threadIdx.x & 63;
    int half = lane >> 5;
    int l = lane & 31;
    bool active = (n < N);
    int nn = active ? n : 0;

    int c0 = l * 4;
    float4 avf = *(const float4*)(att + c0);
    float4 w0f = *(const float4*)(We + c0);
    float4 w1f = *(const float4*)(We + HID + c0);
    h2v avA; avA[0] = (_Float16)avf.x; avA[1] = (_Float16)avf.y;
    h2v avB; avB[0] = (_Float16)avf.z; avB[1] = (_Float16)avf.w;
    h2v weA0; weA0[0] = (_Float16)w0f.x; weA0[1] = (_Float16)w0f.y;
    h2v weB0; weB0[0] = (_Float16)w0f.z; weB0[1] = (_Float16)w0f.w;
    h2v weA1; weA1[0] = (_Float16)w1f.x; weA1[1] = (_Float16)w1f.y;
    h2v weB1; weB1[0] = (_Float16)w1f.z; weB1[1] = (_Float16)w1f.w;
    h2v k02; k02[0] = (_Float16)0.2f; k02[1] = (_Float16)0.2f;

    ushort4 xru = *(const ushort4*)(XR + (size_t)nn * HID + c0);
    h2v xrA = mkh2(xru.x, xru.y), xrB = mkh2(xru.z, xru.w);

    int eb = 0, eend = 0;
    if (active) { eb = row_ptr[n]; eend = row_ptr[n + 1]; }
    int mid = (eb + eend + 1) >> 1;
    int sb = half ? mid : eb;
    int se = half ? eend : mid;

    float l_run = 0.f;
    float4 fa = make_float4(0.f, 0.f, 0.f, 0.f);

    for (int base = sb; base < se; base += 32) {
        int cnt = min(32, se - base);
        int myi = base + l;
        int msrc = 0; unsigned mea = 0;
        if (myi < se) { msrc = csr_src[myi]; mea = csr_eap[myi]; }

        int s0 = __shfl(msrc, 0, 32);
        int s1 = __shfl(msrc, 1, 32);
        unsigned e0 = __shfl(mea, 0, 32);
        unsigned e1 = __shfl(mea, 1, 32);
        ushort4 u0 = *(const ushort4*)(XL + (size_t)s0 * HID + c0);
        ushort4 u1 = *(const ushort4*)(XL + (size_t)s1 * HID + c0);

        for (int j = 0; ; j += 2) {
            bool more = (j + 2 < cnt);
            int ns0 = 0, ns1 = 0; unsigned ne0 = 0, ne1 = 0;
            ushort4 nu0, nu1;
            if (more) {
                ns0 = __shfl(msrc, j + 2, 32);
                ns1 = __shfl(msrc, j + 3, 32);
                ne0 = __shfl(mea, j + 2, 32);
                ne1 = __shfl(mea, j + 3, 32);
                nu0 = *(const ushort4*)(XL + (size_t)ns0 * HID + c0);
                nu1 = *(const ushort4*)(XL + (size_t)ns1 * HID + c0);
            }
            h2v ex0 = splath((unsigned short)(e0 & 0xffff));
            h2v ey0 = splath((unsigned short)(e0 >> 16));
            h2v ex1 = splath((unsigned short)(e1 & 0xffff));
            h2v ey1 = splath((unsigned short)(e1 >> 16));
            h2v xl0A = mkh2(u0.x, u0.y), xl0B = mkh2(u0.z, u0.w);
            h2v xl1A = mkh2(u1.x, u1.y), xl1B = mkh2(u1.z, u1.w);

            h2v mA = xl0A + xrA + ex0 * weA0 + ey0 * weA1;
            mA = __builtin_elementwise_max(mA, k02 * mA);
            h2v mB = xl0B + xrB + ex0 * weB0 + ey0 * weB1;
            mB = __builtin_elementwise_max(mB, k02 * mB);
            float part0 = fdot2v(mB, avB, fdot2v(mA, avA, 0.f));

            h2v nA = xl1A + xrA + ex1 * weA0 + ey1 * weA1;
            nA = __builtin_elementwise_max(nA, k02 * nA);
            h2v nB = xl1B + xrB + ex1 * weB0 + ey1 * weB1;
            nB = __builtin_elementwise_max(nB, k02 * nB);
            float part1 = fdot2v(nB, avB, fdot2v(nA, avA, 0.f));

            float t;
            t = __shfl_xor(part0, 1); part0 += t;
            t = __shfl_xor(part0, 2); part0 += t;
            t = __shfl_xor(part1, 1); part1 += t;
            t = __shfl_xor(part1, 2); part1 += t;

            bool two = (j + 1 < cnt);
            float p0 = __expf(fminf(part0, 60.f));
            float p1 = two ? __expf(fminf(part1, 60.f)) : 0.f;
            l_run += p0 + p1;
            fa.x += p0 * h2f(u0.x) + p1 * h2f(u1.x);
            fa.y += p0 * h2f(u0.y) + p1 * h2f(u1.y);
            fa.z += p0 * h2f(u0.z) + p1 * h2f(u1.z);
            fa.w += p0 * h2f(u0.w) + p1 * h2f(u1.w);
            if (!more) break;
            s0 = ns0; s1 = ns1; e0 = ne0; e1 = ne1; u0 = nu0; u1 = nu1;
        }
    }

    l_run += __shfl_xor(l_run, 32);
    fa.x += __shfl_xor(fa.x, 32);
    fa.y += __shfl_xor(fa.y, 32);
    fa.z += __shfl_xor(fa.z, 32);
    fa.w += __shfl_xor(fa.w, 32);

    if (!active || half) return;
    float inv = 1.f / fmaxf(l_run, 1e-16f);
    float4 bias4 = *(const float4*)(gbias + c0);
    float4 v;
    v.x = fa.x * inv + bias4.x;
    v.y = fa.y * inv + bias4.y;
    v.z = fa.z * inv + bias4.z;
    v.w = fa.w * inv + bias4.w;
    if constexpr (FUSE) {
        ushort4 lu = *(const ushort4*)(lin + (size_t)n * HID + c0);
        v.x += h2f(lu.x); v.y += h2f(lu.y); v.z += h2f(lu.z); v.w += h2f(lu.w);
        v.x = (v.x > 0.f) ? v.x : (__expf(v.x) - 1.f);
        v.y = (v.y > 0.f) ? v.y : (__expf(v.y) - 1.f);
        v.z = (v.z > 0.f) ? v.z : (__expf(v.z) - 1.f);
        v.w = (v.w > 0.f) ? v.w : (__expf(v.w) - 1.f);
    }
    ushort4 hh;
    hh.x = f2h(v.x); hh.y = f2h(v.y); hh.z = f2h(v.z); hh.w = f2h(v.w);
    *(ushort4*)(hb + (size_t)n * HID + c0) = hh;
}

// ---------------------------------------------------------------- mean pool per graph (fp16 input, f32 accumulate)
__global__ __launch_bounds__(128) void pool_kernel(const unsigned short* __restrict__ h,
                                                   const int* __restrict__ batch,
                                                   float* __restrict__ g, int N) {
    int gid = blockIdx.x;
    int lo = lower_bound_i(batch, N, gid);
    int hi = lower_bound_i(batch, N, gid + 1);
    int c4 = threadIdx.x & 31;       // 32 channel-quads
    int sub = threadIdx.x >> 5;      // 4 row-groups
    float4 s = make_float4(0.f, 0.f, 0.f, 0.f);
    for (int i = lo + sub; i < hi; i += 4) {
        ushort4 u = *(const ushort4*)(h + (size_t)i * HID + c4 * 4);
        s.x += h2f(u.x); s.y += h2f(u.y); s.z += h2f(u.z); s.w += h2f(u.w);
    }
    __shared__ float red[4][128];
    *(float4*)&red[sub][c4 * 4] = s;
    __syncthreads();
    if (sub == 0) {
        float4 a = *(float4*)&red[0][c4 * 4];
        float4 b = *(float4*)&red[1][c4 * 4];
        float4 c = *(float4*)&red[2][c4 * 4];
        float4 d = *(float4*)&red[3][c4 * 4];
        float invc = 1.f / fmaxf((float)(hi - lo), 1.0f);
        float4 r;
        r.x = (a.x + b.x + c.x + d.x) * invc;
        r.y = (a.y + b.y + c.y + d.y) * invc;
        r.z = (a.z + b.z + c.z + d.z) * invc;
        r.w = (a.w + b.w + c.w + d.w) * invc;
        *(float4*)(g + (size_t)gid * HID + c4 * 4) = r;
    }
}

// ---------------------------------------------------------------- readout GEMM
__global__ __launch_bounds__(256) void readout_kernel(const float* __restrict__ g,
                                                      const float* __restrict__ W,
                                                      const float* __restrict__ b,
                                                      float* __restrict__ out, int S) {
    __shared__ float gs[HID];
    int gid = blockIdx.y;
    if (threadIdx.x < HID) gs[threadIdx.x] = g[gid * HID + threadIdx.x];
    __syncthreads();
    int c = blockIdx.x * 256 + threadIdx.x;
    if (c < S) {
        float acc = b[c];
        #pragma unroll 8
        for (int k = 0; k < HID; k++) acc += gs[k] * W[(size_t)k * S + c];
        out[(size_t)gid * S + c] = acc;
    }
}

// ---------------------------------------------------------------- launcher
extern "C" void kernel_launch(void* const* d_in, const int* in_sizes, int n_in,
                              void* d_out, int out_size, void* d_ws, size_t ws_size,
                              hipStream_t stream) {
    const float* x      = (const float*)d_in[0];
    const int*   ei     = (const int*)d_in[1];
    const float* eattr  = (const float*)d_in[2];
    const int*   batch  = (const int*)d_in[3];
    const float* at1_Wl = (const float*)d_in[4];
    const float* at1_bl = (const float*)d_in[5];
    const float* at1_Wr = (const float*)d_in[6];
    const float* at1_br = (const float*)d_in[7];
    const float* at1_We = (const float*)d_in[8];
    const float* at1_att= (const float*)d_in[9];
    const float* at1_b  = (const float*)d_in[10];
    const float* l1_W   = (const float*)d_in[11];
    const float* l1_b   = (const float*)d_in[12];
    const float* atk_Wl = (const float*)d_in[13];
    const float* atk_bl = (const float*)d_in[14];
    const float* atk_Wr = (const float*)d_in[15];
    const float* atk_br = (const float*)d_in[16];
    const float* atk_We = (const float*)d_in[17];
    const float* atk_att= (const float*)d_in[18];
    const float* atk_b  = (const float*)d_in[19];
    const float* lk_W   = (const float*)d_in[20];
    const float* lk_b   = (const float*)d_in[21];
    const float* lin_W  = (const float*)d_in[22];
    const float* lin_b  = (const float*)d_in[23];
    float* out = (float*)d_out;

    const int N  = in_sizes[0] / 16;
    const int E  = in_sizes[1] / 2;
    const int ET = E + N;
    const int S  = 1000;
    const int G  = out_size / S;

    char* w = (char*)d_ws;
    auto alloc = [&](size_t bytes) -> char* {
        char* p = w; w += (bytes + 255) & ~(size_t)255; return p;
    };
    unsigned short* XLb = (unsigned short*)alloc((size_t)N * HID * 2);
    unsigned short* XRb = (unsigned short*)alloc((size_t)N * HID * 2);
    unsigned short* Linb = (unsigned short*)alloc((size_t)N * HID * 2);   // also layer-1 Att buffer
    unsigned short* Hb = (unsigned short*)alloc((size_t)N * HID * 2);
    int*    deg     = (int*)alloc((size_t)N * 4);
    int*    row_ptr = (int*)alloc((size_t)(N + 1) * 4);
    int*    cursor  = (int*)alloc((size_t)N * 4);
    int*    csr_src = (int*)alloc((size_t)ET * 4);
    unsigned int* csr_eap = (unsigned int*)alloc((size_t)ET * 4);
    float*  meansum = (float*)alloc(8);
    int*    bsum    = (int*)alloc(256);
    int*    boff    = (int*)alloc(256);
    unsigned short* WlTh = (unsigned short*)alloc((size_t)9 * 16384 * 2);
    unsigned short* WrTh = (unsigned short*)alloc((size_t)9 * 16384 * 2);
    unsigned short* WkTh = (unsigned short*)alloc((size_t)9 * 16384 * 2);
    float*  gpool   = (float*)alloc((size_t)G * HID * 4);
    (void)ws_size; (void)n_in;

    hipError_t err;
    err = hipMemsetAsync(deg, 0, (size_t)N * 4, stream); (void)err;
    err = hipMemsetAsync(meansum, 0, 8, stream); (void)err;

    const int wtot = 9 * 16384;
    wprep_kernel<<<dim3((wtot + 255) / 256, 3), 256, 0, stream>>>(atk_Wl, atk_Wr, lk_W,
                                                                  WlTh, WrTh, WkTh, wtot);

    mean_kernel<<<256, 256, 0, stream>>>(eattr, meansum, E);
    deg_kernel<<<(ET + 255) / 256, 256, 0, stream>>>(ei, deg, E, ET);
    const int NB = (N + 1023) / 1024;
    scanA_kernel<<<NB, 256, 0, stream>>>(deg, bsum, N);
    scanB_kernel<<<1, 64, 0, stream>>>(bsum, boff, row_ptr, NB, N);
    scanC_kernel<<<NB, 256, 0, stream>>>(deg, boff, row_ptr, cursor, N);
    fill_kernel<<<(ET + 255) / 256, 256, 0, stream>>>(ei, eattr, meansum, cursor, csr_src, csr_eap, E, ET);

    const int gx16 = (N + 31) / 32;
    const int ge   = (N + 7) / 8;        // 1 node per wave, 8 waves per 512-thread block
    const int gx3  = (N + 63) / 64;

    transform16_kernel<<<dim3(gx16, 1, 2), 256, 0, stream>>>(x, at1_Wl, at1_bl, XLb, at1_Wr, at1_br, XRb, N);
    edgeh_kernel<0><<<ge, 512, 0, stream>>>(XLb, XRb, row_ptr, csr_src, csr_eap, at1_att, at1_We, at1_b,
                                            nullptr, Linb, N);
    combine16_kernel<<<gx16, 256, 0, stream>>>(x, l1_W, l1_b, Linb, Hb, N);

    for (int i = 0; i < 9; i++) {
        const unsigned short* wlh = WlTh + (size_t)i * 16384;
        const unsigned short* wrh = WrTh + (size_t)i * 16384;
        const unsigned short* wkh = WkTh + (size_t)i * 16384;
        const float* bl = atk_bl + (size_t)i * HID;
        const float* br = atk_br + (size_t)i * HID;
        const float* bk = lk_b   + (size_t)i * HID;
        const float* Wep = atk_We + (size_t)i * 2 * HID;
        const float* at = atk_att + (size_t)i * HID;
        const float* ab = atk_b  + (size_t)i * HID;

        gemm3_kernel<<<gx3, 256, 0, stream>>>(Hb,
                                              wlh, bl, XLb,
                                              wrh, br, XRb,
                                              wkh, bk, Linb, N);
        edgeh_kernel<1><<<ge, 512, 0, stream>>>(XLb, XRb, row_ptr, csr_src, csr_eap, at, Wep, ab,
                                                Linb, Hb, N);
    }

    pool_kernel<<<G, 128, 0, stream>>>(Hb, batch, gpool, N);
    readout_kernel<<<dim3((S + 255) / 256, G), 256, 0, stream>>>(gpool, lin_W, lin_b, out, S);
}

// Round 19
// 652.384 us; speedup vs baseline: 1.2532x; 1.0617x over previous
//
#include <hip/hip_runtime.h>
#include <hip/hip_fp16.h>
#include <cstdint>

#define HID 128

typedef __attribute__((ext_vector_type(8))) _Float16 f16x8;
typedef __attribute__((ext_vector_type(2))) _Float16 h2v;
typedef __attribute__((ext_vector_type(4))) float f32x4;

__device__ __forceinline__ unsigned short f2h(float x) {
    return __builtin_bit_cast(unsigned short, (_Float16)x);
}
__device__ __forceinline__ float h2f(unsigned short u) {
    return (float)__builtin_bit_cast(_Float16, u);
}
__device__ __forceinline__ h2v mkh2(unsigned short a, unsigned short b) {
    unsigned v = (unsigned)a | ((unsigned)b << 16);
    return __builtin_bit_cast(h2v, v);
}
__device__ __forceinline__ h2v splath(unsigned short a) {
    _Float16 h = __builtin_bit_cast(_Float16, a);
    h2v r; r[0] = h; r[1] = h;
    return r;
}
__device__ __forceinline__ float fdot2v(h2v a, h2v b, float c) {
    return __builtin_amdgcn_fdot2(a, b, c, false);
}
__device__ __forceinline__ int lower_bound_i(const int* a, int n, int v) {
    int lo = 0, hi = n;
    while (lo < hi) { int m = (lo + hi) >> 1; if (a[m] < v) lo = m + 1; else hi = m; }
    return lo;
}

// ---------------------------------------------------------------- fused mean + degree: 256 grid-stride blocks
// (keeps meansum wave-atomics at 1024 like the old mean_kernel -- NOT per-element; deg atomics are distributed)
__global__ __launch_bounds__(256) void meandeg_kernel(const int* __restrict__ ei,
                                                      const float* __restrict__ eattr,
                                                      int* __restrict__ deg,
                                                      float* __restrict__ meansum,
                                                      int E, int ET) {
    float sx = 0.f, sy = 0.f;
    for (int i = blockIdx.x * 256 + threadIdx.x; i < ET; i += gridDim.x * 256) {
        int dst = (i < E) ? ei[E + i] : (i - E);
        atomicAdd(&deg[dst], 1);
        if (i < E) {
            float2 v = *(const float2*)(eattr + 2 * (size_t)i);
            sx += v.x; sy += v.y;
        }
    }
    for (int d = 1; d < 64; d <<= 1) { sx += __shfl_xor(sx, d); sy += __shfl_xor(sy, d); }
    if ((threadIdx.x & 63) == 0) { atomicAdd(&meansum[0], sx); atomicAdd(&meansum[1], sy); }
}

__global__ __launch_bounds__(256) void scanA_kernel(const int* __restrict__ deg,
                                                    int* __restrict__ bsum, int N) {
    __shared__ int ws[4];
    int t = threadIdx.x;
    int base = blockIdx.x * 1024 + t * 4;
    int s = 0;
    #pragma unroll
    for (int j = 0; j < 4; j++) { int idx = base + j; if (idx < N) s += deg[idx]; }
    for (int d = 1; d < 64; d <<= 1) s += __shfl_xor(s, d);
    if ((t & 63) == 0) ws[t >> 6] = s;
    __syncthreads();
    if (t == 0) bsum[blockIdx.x] = ws[0] + ws[1] + ws[2] + ws[3];
}

__global__ __launch_bounds__(64) void scanB_kernel(const int* __restrict__ bsum,
                                                   int* __restrict__ boff,
                                                   int* __restrict__ row_ptr, int NB, int N) {
    int t = threadIdx.x;
    int v = (t < NB) ? bsum[t] : 0;
    int inc = v;
    #pragma unroll
    for (int d = 1; d < 64; d <<= 1) { int u = __shfl_up(inc, d); if (t >= d) inc += u; }
    if (t < NB) boff[t] = inc - v;
    if (t == 63) row_ptr[N] = inc;
}

__global__ __launch_bounds__(256) void scanC_kernel(const int* __restrict__ deg,
                                                    const int* __restrict__ boff,
                                                    int* __restrict__ row_ptr,
                                                    int* __restrict__ cursor, int N) {
    __shared__ int wsum[4];
    int t = threadIdx.x;
    int lane = t & 63, wid = t >> 6;
    int base = blockIdx.x * 1024 + t * 4;
    int v[4]; int s = 0;
    #pragma unroll
    for (int j = 0; j < 4; j++) { int idx = base + j; v[j] = (idx < N) ? deg[idx] : 0; s += v[j]; }
    int inc = s;
    #pragma unroll
    for (int d = 1; d < 64; d <<= 1) { int u = __shfl_up(inc, d); if (lane >= d) inc += u; }
    if (lane == 63) wsum[wid] = inc;
    __syncthreads();
    int woff = 0;
    for (int ww = 0; ww < wid; ww++) woff += wsum[ww];
    int excl = boff[blockIdx.x] + woff + inc - s;
    #pragma unroll
    for (int j = 0; j < 4; j++) {
        int idx = base + j;
        if (idx < N) { row_ptr[idx] = excl; cursor[idx] = excl; }
        excl += v[j];
    }
}

__global__ __launch_bounds__(256) void fill_kernel(const int* __restrict__ ei,
                                                   const float* __restrict__ eattr,
                                                   const float* __restrict__ meansum,
                                                   int* __restrict__ cursor,
                                                   int* __restrict__ csr_src,
                                                   unsigned int* __restrict__ csr_eap,
                                                   int E, int ET) {
    int e = blockIdx.x * 256 + threadIdx.x;
    if (e >= ET) return;
    int src, dst; float2 ea;
    if (e < E) {
        src = ei[e]; dst = ei[E + e];
        ea = *(const float2*)(eattr + 2 * (size_t)e);
    } else {
        src = dst = e - E;
        float inv = 1.0f / (float)E;
        ea.x = meansum[0] * inv; ea.y = meansum[1] * inv;
    }
    unsigned pea = (unsigned)f2h(ea.x) | ((unsigned)f2h(ea.y) << 16);   // fp16 pair
    int pos = atomicAdd(&cursor[dst], 1);
    csr_src[pos] = src;
    csr_eap[pos] = pea;
}

// ---------------------------------------------------------------- weight prep: 3 matrices in one dispatch
__global__ __launch_bounds__(256) void wprep_kernel(const float* __restrict__ s0,
                                                    const float* __restrict__ s1,
                                                    const float* __restrict__ s2,
                                                    unsigned short* __restrict__ d0,
                                                    unsigned short* __restrict__ d1,
                                                    unsigned short* __restrict__ d2, int total) {
    int y = blockIdx.y;
    const float* src = (y == 0) ? s0 : (y == 1) ? s1 : s2;
    unsigned short* dst = (y == 0) ? d0 : (y == 1) ? d1 : d2;
    int idx = blockIdx.x * 256 + threadIdx.x;
    if (idx >= total) return;
    int layer = idx >> 14;
    int rem = idx & 16383;
    int n = rem >> 7, k = rem & 127;
    dst[idx] = f2h(src[(layer << 14) | (k << 7) | n]);
}

// ---------------------------------------------------------------- 3-GEMM sequential: A(fp16) loaded ONCE, W(fp16)
// staged per-matrix in LDS; 64-row blocks; swapped operands -> packed ushort4 stores (fp16).
#define LROW 136
__global__ __launch_bounds__(256) void gemm3_kernel(
    const unsigned short* __restrict__ Hb,
    const unsigned short* __restrict__ W0h, const float* __restrict__ b0, unsigned short* __restrict__ o0,
    const unsigned short* __restrict__ W1h, const float* __restrict__ b1, unsigned short* __restrict__ o1,
    const unsigned short* __restrict__ W2h, const float* __restrict__ b2, unsigned short* __restrict__ o2,
    int N) {
    __shared__ unsigned short lds_h[128 * LROW];
    int tid = threadIdx.x;
    int wid = tid >> 6, lane = tid & 63;
    int row0 = blockIdx.x * 64 + wid * 16;
    int lr = lane & 15;
    int cgrp = lane >> 4;
    int kb = cgrp * 8;
    bool rowsok = (row0 < N);

    f16x8 ha[4];
    {
        int node = row0 + lr;
        int nodec = rowsok ? ((node < N) ? node : (N - 1)) : 0;
        const unsigned short* pa = Hb + (size_t)nodec * HID + kb;
        #pragma unroll
        for (int kf = 0; kf < 4; kf++) ha[kf] = *(const f16x8*)(pa + kf * 32);
    }

    const unsigned short* Whs[3] = {W0h, W1h, W2h};
    const float* Bs[3] = {b0, b1, b2};
    unsigned short* Os[3] = {o0, o1, o2};

    for (int w = 0; w < 3; w++) {
        if (w) __syncthreads();
        const unsigned short* sh = Whs[w];
        #pragma unroll
        for (int j = 0; j < 8; j++) {
            int c = tid + 256 * j;
            int r = c >> 4, col = (c & 15) * 8;
            *(f16x8*)&lds_h[r * LROW + col] = *(const f16x8*)(sh + r * HID + col);
        }
        __syncthreads();
        if (!rowsok) continue;

        const float* bias = Bs[w];
        unsigned short* outp = Os[w];
        #pragma unroll 2
        for (int nf = 0; nf < 8; nf++) {
            int wrow = nf * 16 + lr;
            const unsigned short* ph = &lds_h[wrow * LROW + kb];
            f16x8 wf[4];
            #pragma unroll
            for (int kf = 0; kf < 4; kf++) wf[kf] = *(const f16x8*)(ph + kf * 32);
            f32x4 acc = {0.f, 0.f, 0.f, 0.f};
            #pragma unroll
            for (int kf = 0; kf < 4; kf++)
                acc = __builtin_amdgcn_mfma_f32_16x16x32_f16(wf[kf], ha[kf], acc, 0, 0, 0);
            int chb = nf * 16 + cgrp * 4;
            float4 bias4 = *(const float4*)(bias + chb);
            int node = row0 + lr;
            ushort4 u;
            u.x = f2h(acc[0] + bias4.x); u.y = f2h(acc[1] + bias4.y);
            u.z = f2h(acc[2] + bias4.z); u.w = f2h(acc[3] + bias4.w);
            if (node < N) *(ushort4*)(outp + (size_t)node * HID + chb) = u;
        }
    }
}

// ---------------------------------------------------------------- layer-1 transform (K=16, f32 in -> fp16 out)
__global__ __launch_bounds__(256) void transform16_kernel(
    const float* __restrict__ Hin,
    const float* __restrict__ W0, const float* __restrict__ b0, unsigned short* __restrict__ o0,
    const float* __restrict__ W1, const float* __restrict__ b1, unsigned short* __restrict__ o1,
    int N) {
    constexpr int K = 16;
    __shared__ float Ws[K][HID];
    __shared__ float Hs[32][K + 4];

    const float* W; const float* bias; unsigned short* outp;
    if (blockIdx.z == 0) { W = W0; bias = b0; outp = o0; }
    else                 { W = W1; bias = b1; outp = o1; }

    int row0 = blockIdx.x * 32;
    int tid = threadIdx.x;
    int tx = tid & 15, ty = tid >> 4;

    for (int i = tid; i < 32 * (K / 4); i += 256) {
        int r = i / (K / 4), kq = i % (K / 4);
        int row = row0 + r;
        float4 v = make_float4(0.f, 0.f, 0.f, 0.f);
        if (row < N) v = *(const float4*)(Hin + (size_t)row * K + kq * 4);
        *(float4*)&Hs[r][kq * 4] = v;
    }
    for (int i = tid; i < K * 32; i += 256) {
        int k = i >> 5, cq = i & 31;
        *(float4*)&Ws[k][cq * 4] = *(const float4*)(W + (size_t)k * HID + cq * 4);
    }
    __syncthreads();

    float acc[2][8];
    #pragma unroll
    for (int i = 0; i < 2; i++)
        #pragma unroll
        for (int j = 0; j < 8; j++) acc[i][j] = 0.f;

    int r0 = ty * 2, r1 = ty * 2 + 1;
    #pragma unroll
    for (int k = 0; k < K; k++) {
        float a0 = Hs[r0][k];
        float a1 = Hs[r1][k];
        float4 w0 = *(float4*)&Ws[k][tx * 4];
        float4 w1 = *(float4*)&Ws[k][64 + tx * 4];
        acc[0][0] += a0 * w0.x; acc[0][1] += a0 * w0.y; acc[0][2] += a0 * w0.z; acc[0][3] += a0 * w0.w;
        acc[0][4] += a0 * w1.x; acc[0][5] += a0 * w1.y; acc[0][6] += a0 * w1.z; acc[0][7] += a0 * w1.w;
        acc[1][0] += a1 * w0.x; acc[1][1] += a1 * w0.y; acc[1][2] += a1 * w0.z; acc[1][3] += a1 * w0.w;
        acc[1][4] += a1 * w1.x; acc[1][5] += a1 * w1.y; acc[1][6] += a1 * w1.z; acc[1][7] += a1 * w1.w;
    }

    float4 bb0 = *(const float4*)(bias + tx * 4);
    float4 bb1 = *(const float4*)(bias + 64 + tx * 4);
    #pragma unroll
    for (int i = 0; i < 2; i++) {
        int row = row0 + ty * 2 + i;
        if (row < N) {
            ushort4 h0, h1;
            h0.x = f2h(acc[i][0] + bb0.x); h0.y = f2h(acc[i][1] + bb0.y);
            h0.z = f2h(acc[i][2] + bb0.z); h0.w = f2h(acc[i][3] + bb0.w);
            h1.x = f2h(acc[i][4] + bb1.x); h1.y = f2h(acc[i][5] + bb1.y);
            h1.z = f2h(acc[i][6] + bb1.z); h1.w = f2h(acc[i][7] + bb1.w);
            *(ushort4*)(outp + (size_t)row * HID + tx * 4) = h0;
            *(ushort4*)(outp + (size_t)row * HID + 64 + tx * 4) = h1;
        }
    }
}

// ---------------------------------------------------------------- layer-1 combine: Hb = fp16(elu(att(fp16) + x@W + b))
__global__ __launch_bounds__(256) void combine16_kernel(
    const float* __restrict__ Hin,
    const float* __restrict__ W, const float* __restrict__ bias,
    const unsigned short* __restrict__ Att, unsigned short* __restrict__ Hb,
    int N) {
    constexpr int K = 16;
    __shared__ float Ws[K][HID];
    __shared__ float Hs[32][K + 4];

    int row0 = blockIdx.x * 32;
    int tid = threadIdx.x;
    int tx = tid & 15, ty = tid >> 4;

    for (int i = tid; i < 32 * (K / 4); i += 256) {
        int r = i / (K / 4), kq = i % (K / 4);
        int row = row0 + r;
        float4 v = make_float4(0.f, 0.f, 0.f, 0.f);
        if (row < N) v = *(const float4*)(Hin + (size_t)row * K + kq * 4);
        *(float4*)&Hs[r][kq * 4] = v;
    }
    for (int i = tid; i < K * 32; i += 256) {
        int k = i >> 5, cq = i & 31;
        *(float4*)&Ws[k][cq * 4] = *(const float4*)(W + (size_t)k * HID + cq * 4);
    }
    __syncthreads();

    float acc[2][8];
    #pragma unroll
    for (int i = 0; i < 2; i++)
        #pragma unroll
        for (int j = 0; j < 8; j++) acc[i][j] = 0.f;

    int r0 = ty * 2, r1 = ty * 2 + 1;
    #pragma unroll
    for (int k = 0; k < K; k++) {
        float a0 = Hs[r0][k];
        float a1 = Hs[r1][k];
        float4 w0 = *(float4*)&Ws[k][tx * 4];
        float4 w1 = *(float4*)&Ws[k][64 + tx * 4];
        acc[0][0] += a0 * w0.x; acc[0][1] += a0 * w0.y; acc[0][2] += a0 * w0.z; acc[0][3] += a0 * w0.w;
        acc[0][4] += a0 * w1.x; acc[0][5] += a0 * w1.y; acc[0][6] += a0 * w1.z; acc[0][7] += a0 * w1.w;
        acc[1][0] += a1 * w0.x; acc[1][1] += a1 * w0.y; acc[1][2] += a1 * w0.z; acc[1][3] += a1 * w0.w;
        acc[1][4] += a1 * w1.x; acc[1][5] += a1 * w1.y; acc[1][6] += a1 * w1.z; acc[1][7] += a1 * w1.w;
    }

    float4 bb0 = *(const float4*)(bias + tx * 4);
    float4 bb1 = *(const float4*)(bias + 64 + tx * 4);
    #pragma unroll
    for (int i = 0; i < 2; i++) {
        int row = row0 + ty * 2 + i;
        if (row < N) {
            const unsigned short* p0 = Att + (size_t)row * HID + tx * 4;
            ushort4 g0 = *(const ushort4*)p0;
            ushort4 g1 = *(const ushort4*)(p0 + 64);
            float v[8];
            v[0] = h2f(g0.x) + acc[i][0] + bb0.x; v[1] = h2f(g0.y) + acc[i][1] + bb0.y;
            v[2] = h2f(g0.z) + acc[i][2] + bb0.z; v[3] = h2f(g0.w) + acc[i][3] + bb0.w;
            v[4] = h2f(g1.x) + acc[i][4] + bb1.x; v[5] = h2f(g1.y) + acc[i][5] + bb1.y;
            v[6] = h2f(g1.z) + acc[i][6] + bb1.z; v[7] = h2f(g1.w) + acc[i][7] + bb1.w;
            #pragma unroll
            for (int j = 0; j < 8; j++) v[j] = (v[j] > 0.f) ? v[j] : (__expf(v[j]) - 1.f);
            ushort4 h0, h1;
            h0.x = f2h(v[0]); h0.y = f2h(v[1]); h0.z = f2h(v[2]); h0.w = f2h(v[3]);
            h1.x = f2h(v[4]); h1.y = f2h(v[5]); h1.z = f2h(v[6]); h1.w = f2h(v[7]);
            *(ushort4*)(Hb + (size_t)row * HID + tx * 4) = h0;
            *(ushort4*)(Hb + (size_t)row * HID + 64 + tx * 4) = h1;
        }
    }
}

// ---------------------------------------------------------------- edge: packed _Float16 vector math.
// TWO nodes/wave: each 32-lane half owns one full node (params amortized, NO cross-half merge).
// No running max (logits O(1), clamp 60); plain-sum accumulators; 1-pair-ahead prefetch.
// FUSE=0 (layer 1): att+gbias -> fp16 hb.  FUSE=1: +lin, elu -> fp16 hb.
template <int FUSE>
__global__ __launch_bounds__(512) void edgeh_kernel(
    const unsigned short* __restrict__ XL, const unsigned short* __restrict__ XR,
    const int* __restrict__ row_ptr, const int* __restrict__ csr_src,
    const unsigned int* __restrict__ csr_eap,
    const float* __restrict__ att,
    const float* __restrict__ We,
    const float* __restrict__ gbias,
    const unsigned short* __restrict__ lin,
    unsigned short* __restrict__ hb,
    int N) {
    int wv = (blockIdx.x * 512 + threadIdx.x) >> 6;
    int lane = threadIdx.x & 63;
    int half = lane >> 5;
    int l = lane & 31;
    int n = wv * 2 + half;             // this half's node
    bool active = (n < N);
    int nn = active ? n : 0;

    int c0 = l * 4;
    float4 avf = *(const float4*)(att + c0);
    float4 w0f = *(const float4*)(We + c0);
    float4 w1f = *(const float4*)(We + HID + c0);
    h2v avA; avA[0] = (_Float16)avf.x; avA[1] = (_Float16)avf.y;
    h2v avB; avB[0] = (_Float16)avf.z; avB[1] = (_Float16)avf.w;
    h2v weA0; weA0[0] = (_Float16)w0f.x; weA0[1] = (_Float16)w0f.y;
    h2v weB0; weB0[0] = (_Float16)w0f.z; weB0[1] = (_Float16)w0f.w;
    h2v weA1; weA1[0] = (_Float16)w1f.x; weA1[1] = (_Float16)w1f.y;
    h2v weB1; weB1[0] = (_Float16)w1f.z; weB1[1] = (_Float16)w1f.w;
    h2v k02; k02[0] = (_Float16)0.2f; k02[1] = (_Float16)0.2f;

    ushort4 xru = *(const ushort4*)(XR + (size_t)nn * HID + c0);
    h2v xrA = mkh2(xru.x, xru.y), xrB = mkh2(xru.z, xru.w);

    int sb = 0, se = 0;
    if (active) { sb = row_ptr[n]; se = row_ptr[n + 1]; }

    float l_run = 0.f;
    float4 fa = make_float4(0.f, 0.f, 0.f, 0.f);

    for (int base = sb; base < se; base += 32) {
        int cnt = min(32, se - base);
        int myi = base + l;
        int msrc = 0; unsigned mea = 0;
        if (myi < se) { msrc = csr_src[myi]; mea = csr_eap[myi]; }

        int s0 = __shfl(msrc, 0, 32);          // width-32: broadcasts within this half
        int s1 = __shfl(msrc, 1, 32);
        unsigned e0 = __shfl(mea, 0, 32);
        unsigned e1 = __shfl(mea, 1, 32);
        ushort4 u0 = *(const ushort4*)(XL + (size_t)s0 * HID + c0);
        ushort4 u1 = *(const ushort4*)(XL + (size_t)s1 * HID + c0);

        for (int j = 0; ; j += 2) {
            bool more = (j + 2 < cnt);
            int ns0 = 0, ns1 = 0; unsigned ne0 = 0, ne1 = 0;
            ushort4 nu0, nu1;
            if (more) {
                ns0 = __shfl(msrc, j + 2, 32);
                ns1 = __shfl(msrc, j + 3, 32);
                ne0 = __shfl(mea, j + 2, 32);
                ne1 = __shfl(mea, j + 3, 32);
                nu0 = *(const ushort4*)(XL + (size_t)ns0 * HID + c0);
                nu1 = *(const ushort4*)(XL + (size_t)ns1 * HID + c0);
            }
            h2v ex0 = splath((unsigned short)(e0 & 0xffff));
            h2v ey0 = splath((unsigned short)(e0 >> 16));
            h2v ex1 = splath((unsigned short)(e1 & 0xffff));
            h2v ey1 = splath((unsigned short)(e1 >> 16));
            h2v xl0A = mkh2(u0.x, u0.y), xl0B = mkh2(u0.z, u0.w);
            h2v xl1A = mkh2(u1.x, u1.y), xl1B = mkh2(u1.z, u1.w);

            h2v mA = xl0A + xrA + ex0 * weA0 + ey0 * weA1;
            mA = __builtin_elementwise_max(mA, k02 * mA);
            h2v mB = xl0B + xrB + ex0 * weB0 + ey0 * weB1;
            mB = __builtin_elementwise_max(mB, k02 * mB);
            float part0 = fdot2v(mB, avB, fdot2v(mA, avA, 0.f));

            h2v nA = xl1A + xrA + ex1 * weA0 + ey1 * weA1;
            nA = __builtin_elementwise_max(nA, k02 * nA);
            h2v nB = xl1B + xrB + ex1 * weB0 + ey1 * weB1;
            nB = __builtin_elementwise_max(nB, k02 * nB);
            float part1 = fdot2v(nB, avB, fdot2v(nA, avA, 0.f));

            float t;
            t = __shfl_xor(part0, 1); part0 += t;
            t = __shfl_xor(part0, 2); part0 += t;
            t = __shfl_xor(part1, 1); part1 += t;
            t = __shfl_xor(part1, 2); part1 += t;

            bool two = (j + 1 < cnt);
            float p0 = __expf(fminf(part0, 60.f));
            float p1 = two ? __expf(fminf(part1, 60.f)) : 0.f;
            l_run += p0 + p1;
            fa.x += p0 * h2f(u0.x) + p1 * h2f(u1.x);
            fa.y += p0 * h2f(u0.y) + p1 * h2f(u1.y);
            fa.z += p0 * h2f(u0.z) + p1 * h2f(u1.z);
            fa.w += p0 * h2f(u0.w) + p1 * h2f(u1.w);
            if (!more) break;
            s0 = ns0; s1 = ns1; e0 = ne0; e1 = ne1; u0 = nu0; u1 = nu1;
        }
    }

    if (!active) return;               // each half writes its own node; no merge
    float inv = 1.f / fmaxf(l_run, 1e-16f);
    float4 bias4 = *(const float4*)(gbias + c0);
    float4 v;
    v.x = fa.x * inv + bias4.x;
    v.y = fa.y * inv + bias4.y;
    v.z = fa.z * inv + bias4.z;
    v.w = fa.w * inv + bias4.w;
    if constexpr (FUSE) {
        ushort4 lu = *(const ushort4*)(lin + (size_t)n * HID + c0);
        v.x += h2f(lu.x); v.y += h2f(lu.y); v.z += h2f(lu.z); v.w += h2f(lu.w);
        v.x = (v.x > 0.f) ? v.x : (__expf(v.x) - 1.f);
        v.y = (v.y > 0.f) ? v.y : (__expf(v.y) - 1.f);
        v.z = (v.z > 0.f) ? v.z : (__expf(v.z) - 1.f);
        v.w = (v.w > 0.f) ? v.w : (__expf(v.w) - 1.f);
    }
    ushort4 hh;
    hh.x = f2h(v.x); hh.y = f2h(v.y); hh.z = f2h(v.z); hh.w = f2h(v.w);
    *(ushort4*)(hb + (size_t)n * HID + c0) = hh;
}

// ---------------------------------------------------------------- mean pool per graph (fp16 input, f32 accumulate)
__global__ __launch_bounds__(128) void pool_kernel(const unsigned short* __restrict__ h,
                                                   const int* __restrict__ batch,
                                                   float* __restrict__ g, int N) {
    int gid = blockIdx.x;
    int lo = lower_bound_i(batch, N, gid);
    int hi = lower_bound_i(batch, N, gid + 1);
    int c4 = threadIdx.x & 31;       // 32 channel-quads
    int sub = threadIdx.x >> 5;      // 4 row-groups
    float4 s = make_float4(0.f, 0.f, 0.f, 0.f);
    for (int i = lo + sub; i < hi; i += 4) {
        ushort4 u = *(const ushort4*)(h + (size_t)i * HID + c4 * 4);
        s.x += h2f(u.x); s.y += h2f(u.y); s.z += h2f(u.z); s.w += h2f(u.w);
    }
    __shared__ float red[4][128];
    *(float4*)&red[sub][c4 * 4] = s;
    __syncthreads();
    if (sub == 0) {
        float4 a = *(float4*)&red[0][c4 * 4];
        float4 b = *(float4*)&red[1][c4 * 4];
        float4 c = *(float4*)&red[2][c4 * 4];
        float4 d = *(float4*)&red[3][c4 * 4];
        float invc = 1.f / fmaxf((float)(hi - lo), 1.0f);
        float4 r;
        r.x = (a.x + b.x + c.x + d.x) * invc;
        r.y = (a.y + b.y + c.y + d.y) * invc;
        r.z = (a.z + b.z + c.z + d.z) * invc;
        r.w = (a.w + b.w + c.w + d.w) * invc;
        *(float4*)(g + (size_t)gid * HID + c4 * 4) = r;
    }
}

// ---------------------------------------------------------------- readout GEMM
__global__ __launch_bounds__(256) void readout_kernel(const float* __restrict__ g,
                                                      const float* __restrict__ W,
                                                      const float* __restrict__ b,
                                                      float* __restrict__ out, int S) {
    __shared__ float gs[HID];
    int gid = blockIdx.y;
    if (threadIdx.x < HID) gs[threadIdx.x] = g[gid * HID + threadIdx.x];
    __syncthreads();
    int c = blockIdx.x * 256 + threadIdx.x;
    if (c < S) {
        float acc = b[c];
        #pragma unroll 8
        for (int k = 0; k < HID; k++) acc += gs[k] * W[(size_t)k * S + c];
        out[(size_t)gid * S + c] = acc;
    }
}

// ---------------------------------------------------------------- launcher
extern "C" void kernel_launch(void* const* d_in, const int* in_sizes, int n_in,
                              void* d_out, int out_size, void* d_ws, size_t ws_size,
                              hipStream_t stream) {
    const float* x      = (const float*)d_in[0];
    const int*   ei     = (const int*)d_in[1];
    const float* eattr  = (const float*)d_in[2];
    const int*   batch  = (const int*)d_in[3];
    const float* at1_Wl = (const float*)d_in[4];
    const float* at1_bl = (const float*)d_in[5];
    const float* at1_Wr = (const float*)d_in[6];
    const float* at1_br = (const float*)d_in[7];
    const float* at1_We = (const float*)d_in[8];
    const float* at1_att= (const float*)d_in[9];
    const float* at1_b  = (const float*)d_in[10];
    const float* l1_W   = (const float*)d_in[11];
    const float* l1_b   = (const float*)d_in[12];
    const float* atk_Wl = (const float*)d_in[13];
    const float* atk_bl = (const float*)d_in[14];
    const float* atk_Wr = (const float*)d_in[15];
    const float* atk_br = (const float*)d_in[16];
    const float* atk_We = (const float*)d_in[17];
    const float* atk_att= (const float*)d_in[18];
    const float* atk_b  = (const float*)d_in[19];
    const float* lk_W   = (const float*)d_in[20];
    const float* lk_b   = (const float*)d_in[21];
    const float* lin_W  = (const float*)d_in[22];
    const float* lin_b  = (const float*)d_in[23];
    float* out = (float*)d_out;

    const int N  = in_sizes[0] / 16;
    const int E  = in_sizes[1] / 2;
    const int ET = E + N;
    const int S  = 1000;
    const int G  = out_size / S;

    char* w = (char*)d_ws;
    auto alloc = [&](size_t bytes) -> char* {
        char* p = w; w += (bytes + 255) & ~(size_t)255; return p;
    };
    unsigned short* XLb = (unsigned short*)alloc((size_t)N * HID * 2);
    unsigned short* XRb = (unsigned short*)alloc((size_t)N * HID * 2);
    unsigned short* Linb = (unsigned short*)alloc((size_t)N * HID * 2);   // also layer-1 Att buffer
    unsigned short* Hb = (unsigned short*)alloc((size_t)N * HID * 2);
    int*    deg     = (int*)alloc((size_t)N * 4);
    int*    row_ptr = (int*)alloc((size_t)(N + 1) * 4);
    int*    cursor  = (int*)alloc((size_t)N * 4);
    int*    csr_src = (int*)alloc((size_t)ET * 4);
    unsigned int* csr_eap = (unsigned int*)alloc((size_t)ET * 4);
    float*  meansum = (float*)alloc(8);
    int*    bsum    = (int*)alloc(256);
    int*    boff    = (int*)alloc(256);
    unsigned short* WlTh = (unsigned short*)alloc((size_t)9 * 16384 * 2);
    unsigned short* WrTh = (unsigned short*)alloc((size_t)9 * 16384 * 2);
    unsigned short* WkTh = (unsigned short*)alloc((size_t)9 * 16384 * 2);
    float*  gpool   = (float*)alloc((size_t)G * HID * 4);
    (void)ws_size; (void)n_in;

    hipError_t err;
    err = hipMemsetAsync(deg, 0, (size_t)N * 4, stream); (void)err;
    err = hipMemsetAsync(meansum, 0, 8, stream); (void)err;

    const int wtot = 9 * 16384;
    wprep_kernel<<<dim3((wtot + 255) / 256, 3), 256, 0, stream>>>(atk_Wl, atk_Wr, lk_W,
                                                                  WlTh, WrTh, WkTh, wtot);

    meandeg_kernel<<<256, 256, 0, stream>>>(ei, eattr, deg, meansum, E, ET);
    const int NB = (N + 1023) / 1024;
    scanA_kernel<<<NB, 256, 0, stream>>>(deg, bsum, N);
    scanB_kernel<<<1, 64, 0, stream>>>(bsum, boff, row_ptr, NB, N);
    scanC_kernel<<<NB, 256, 0, stream>>>(deg, boff, row_ptr, cursor, N);
    fill_kernel<<<(ET + 255) / 256, 256, 0, stream>>>(ei, eattr, meansum, cursor, csr_src, csr_eap, E, ET);

    const int gx16 = (N + 31) / 32;
    const int ge   = (N + 15) / 16;      // 2 nodes per wave, 8 waves per 512-thread block
    const int gx3  = (N + 63) / 64;

    transform16_kernel<<<dim3(gx16, 1, 2), 256, 0, stream>>>(x, at1_Wl, at1_bl, XLb, at1_Wr, at1_br, XRb, N);
    edgeh_kernel<0><<<ge, 512, 0, stream>>>(XLb, XRb, row_ptr, csr_src, csr_eap, at1_att, at1_We, at1_b,
                                            nullptr, Linb, N);
    combine16_kernel<<<gx16, 256, 0, stream>>>(x, l1_W, l1_b, Linb, Hb, N);

    for (int i = 0; i < 9; i++) {
        const unsigned short* wlh = WlTh + (size_t)i * 16384;
        const unsigned short* wrh = WrTh + (size_t)i * 16384;
        const unsigned short* wkh = WkTh + (size_t)i * 16384;
        const float* bl = atk_bl + (size_t)i * HID;
        const float* br = atk_br + (size_t)i * HID;
        const float* bk = lk_b   + (size_t)i * HID;
        const float* Wep = atk_We + (size_t)i * 2 * HID;
        const float* at = atk_att + (size_t)i * HID;
        const float* ab = atk_b  + (size_t)i * HID;

        gemm3_kernel<<<gx3, 256, 0, stream>>>(Hb,
                                              wlh, bl, XLb,
                                              wrh, br, XRb,
                                              wkh, bk, Linb, N);
        edgeh_kernel<1><<<ge, 512, 0, stream>>>(XLb, XRb, row_ptr, csr_src, csr_eap, at, Wep, ab,
                                                Linb, Hb, N);
    }

    pool_kernel<<<G, 128, 0, stream>>>(Hb, batch, gpool, N);
    readout_kernel<<<dim3((S + 255) / 256, G), 256, 0, stream>>>(gpool, lin_W, lin_b, out, S);
}